// Round 4
// baseline (1413.433 us; speedup 1.0000x reference)
//
#include <hip/hip_runtime.h>
#include <hip/hip_bf16.h>
#include <stdint.h>

// Problem constants (from reference)
#define NN 50000
#define NE 800000
#define DV 133
#define DE 14
#define DH 300
#define LDH 320   // padded row stride (shorts) for all node-state buffers

typedef unsigned short ushort_t;
typedef __attribute__((ext_vector_type(8))) short short8;
typedef __attribute__((ext_vector_type(4))) float f32x4;

__device__ __forceinline__ float bf2f(ushort_t u) {
  union { unsigned int i; float f; } v; v.i = ((unsigned int)u) << 16; return v.f;
}
__device__ __forceinline__ ushort_t f2bf(float f) {
  union { unsigned int i; float f; } v; v.f = f;
  unsigned int u = v.i;
  return (ushort_t)((u + 0x7fffu + ((u >> 16) & 1u)) >> 16);
}
__device__ __forceinline__ float u_lo(unsigned int u) {
  union { unsigned int i; float f; } v; v.i = u << 16; return v.f;
}
__device__ __forceinline__ float u_hi(unsigned int u) {
  union { unsigned int i; float f; } v; v.i = u & 0xffff0000u; return v.f;
}

// ---------------- edge_index dtype detection (int64 vs int32) ----------------
__global__ void detect_kernel(const int* __restrict__ ei32, int* __restrict__ flag) {
  __shared__ int s_or;
  if (threadIdx.x == 0) s_or = 0;
  __syncthreads();
  int v = ei32[2 * threadIdx.x + 1] | ei32[2 * (threadIdx.x + 256) + 1] |
          ei32[2 * (threadIdx.x + 512) + 1] | ei32[2 * (threadIdx.x + 768) + 1];
  if (v) atomicOr(&s_or, 1);
  __syncthreads();
  if (threadIdx.x == 0) *flag = (s_or == 0) ? 1 : 0;
}

__global__ void decode_kernel(const void* __restrict__ ei_raw, const int* __restrict__ flag,
                              int* __restrict__ src32, int* __restrict__ dst32) {
  int e = blockIdx.x * blockDim.x + threadIdx.x;
  if (e >= NE) return;
  if (*flag) {
    const long long* p = (const long long*)ei_raw;
    src32[e] = (int)p[e];
    dst32[e] = (int)p[NE + e];
  } else {
    const int* p = (const int*)ei_raw;
    src32[e] = p[e];
    dst32[e] = p[NE + e];
  }
}

// ---------------- conversion: f32 submatrix -> zero-padded bf16 ----------------
__global__ void convert_pad_kernel(const float* __restrict__ src, int src_ld, int col_off,
                                   int rows, int cols, ushort_t* __restrict__ dst, int dst_ld,
                                   long total) {
  long gid = (long)blockIdx.x * blockDim.x + threadIdx.x;
  if (gid >= total) return;
  int r = (int)(gid / dst_ld), c = (int)(gid % dst_ld);
  float v = (r < rows && c < cols) ? src[(long)r * src_ld + col_off + c] : 0.f;
  dst[gid] = f2bf(v);
}

// ---------------- per-dst edge-feature sums + degree counts ----------------
__global__ void esum_count_kernel(const int* __restrict__ dst32, const float* __restrict__ Ef,
                                  float* __restrict__ Esum, int* __restrict__ counts) {
  int gid = blockIdx.x * blockDim.x + threadIdx.x;
  int e = gid >> 4, k = gid & 15;
  if (e >= NE) return;
  int dst = dst32[e];
  if (k < DE) atomicAdd(&Esum[dst * DE + k], Ef[(long)e * DE + k]);
  if (k == 15) atomicAdd(&counts[dst], 1);
}

// ---------------- parallel scan (3 kernels) ----------------
__global__ void scan1_kernel(const int* __restrict__ counts, int* __restrict__ local,
                             int* __restrict__ bsums, int n) {
  __shared__ int wsum[4];
  int b = blockIdx.x, t = threadIdx.x;
  int i = b * 256 + t;
  int v = (i < n) ? counts[i] : 0;
  int lane = t & 63, wid = t >> 6;
  int x = v;
#pragma unroll
  for (int d = 1; d < 64; d <<= 1) {
    int y = __shfl_up(x, d);
    if (lane >= d) x += y;
  }
  if (lane == 63) wsum[wid] = x;
  __syncthreads();
  int add = 0;
  for (int k = 0; k < wid; k++) add += wsum[k];
  int incl = x + add;
  if (i < n) local[i] = incl - v;
  if (t == 255) bsums[b] = incl;
}

__global__ void scan2_kernel(int* __restrict__ bsums, int nb) {
  __shared__ int buf[256];
  int t = threadIdx.x;
  int v = (t < nb) ? bsums[t] : 0;
  buf[t] = v;
  __syncthreads();
  for (int d = 1; d < 256; d <<= 1) {
    int a = (t >= d) ? buf[t - d] : 0;
    __syncthreads();
    buf[t] += a;
    __syncthreads();
  }
  if (t < nb) bsums[t] = buf[t] - v;  // exclusive
}

__global__ void scan3_kernel(const int* __restrict__ local, const int* __restrict__ bsums,
                             int* __restrict__ rp, int* __restrict__ cursor, int n) {
  int i = blockIdx.x * 256 + threadIdx.x;
  if (i > n) return;
  int v = (i < n) ? (local[i] + bsums[i >> 8]) : NE;
  rp[i] = v;
  if (i < n) cursor[i] = v;
}

// ---------------- CSR fill: bucket src ids by dst ----------------
__global__ void fill_kernel(const int* __restrict__ src32, const int* __restrict__ dst32,
                            int* __restrict__ cursor, int* __restrict__ ssrc) {
  int e = blockIdx.x * blockDim.x + threadIdx.x;
  if (e >= NE) return;
  int dst = dst32[e];
  int pos = atomicAdd(&cursor[dst], 1);
  ssrc[pos] = src32[e];
}

// ---------------- constant term C = Esum @ W_hE^T + deg * b_h ----------------
__global__ void cterm_kernel(const float* __restrict__ Esum, const int* __restrict__ rp,
                             const float* __restrict__ W_h, const float* __restrict__ b_h,
                             ushort_t* __restrict__ Cb) {
  int n = blockIdx.y;
  int j = blockIdx.x * blockDim.x + threadIdx.x;
  if (j >= DH) return;
  float deg = (float)(rp[n + 1] - rp[n]);
  float acc = deg * b_h[j];
#pragma unroll
  for (int k = 0; k < DE; k++) acc += Esum[n * DE + k] * W_h[j * (DH + DE) + DH + k];
  Cb[(long)n * LDH + j] = f2bf(acc);
}

// ---------------- segment-sum via CSR gather: A[n] = sum_{e:dst=n} H[src_e] ----------------
// one wave per node; row = 320 bf16 = 640B = 40 lanes x 16B
__global__ void gather_kernel(const ushort_t* __restrict__ H, const int* __restrict__ rp,
                              const int* __restrict__ ssrc, ushort_t* __restrict__ A) {
  int wave = blockIdx.x * (blockDim.x >> 6) + (threadIdx.x >> 6);
  int lane = threadIdx.x & 63;
  if (wave >= NN || lane >= 40) return;
  int start = rp[wave], end = rp[wave + 1];
  float a0 = 0, a1 = 0, a2 = 0, a3 = 0, a4 = 0, a5 = 0, a6 = 0, a7 = 0;
  const uint4* base = (const uint4*)H;  // 40 uint4 per row
  int i = start;
  for (; i + 1 < end; i += 2) {
    int s0 = ssrc[i], s1 = ssrc[i + 1];
    uint4 x = base[(long)s0 * 40 + lane];
    uint4 y = base[(long)s1 * 40 + lane];
    a0 += u_lo(x.x); a1 += u_hi(x.x); a2 += u_lo(x.y); a3 += u_hi(x.y);
    a4 += u_lo(x.z); a5 += u_hi(x.z); a6 += u_lo(x.w); a7 += u_hi(x.w);
    a0 += u_lo(y.x); a1 += u_hi(y.x); a2 += u_lo(y.y); a3 += u_hi(y.y);
    a4 += u_lo(y.z); a5 += u_hi(y.z); a6 += u_lo(y.w); a7 += u_hi(y.w);
  }
  if (i < end) {
    int s0 = ssrc[i];
    uint4 x = base[(long)s0 * 40 + lane];
    a0 += u_lo(x.x); a1 += u_hi(x.x); a2 += u_lo(x.y); a3 += u_hi(x.y);
    a4 += u_lo(x.z); a5 += u_hi(x.z); a6 += u_lo(x.w); a7 += u_hi(x.w);
  }
  uint4 o;
  o.x = (unsigned int)f2bf(a0) | ((unsigned int)f2bf(a1) << 16);
  o.y = (unsigned int)f2bf(a2) | ((unsigned int)f2bf(a3) << 16);
  o.z = (unsigned int)f2bf(a4) | ((unsigned int)f2bf(a5) << 16);
  o.w = (unsigned int)f2bf(a6) | ((unsigned int)f2bf(a7) << 16);
  ((uint4*)A)[(long)wave * 40 + lane] = o;
}

// ---------------- bf16 MFMA GEMM: out = relu(A1@W1^T [+ A2@W2^T] + bias + add1 + add2) ----
// block: 256 thr = 4 waves; tile = 64 rows x 304 cols (19 col-frags of 16).
// Wave w owns col-frags cf = w + 4*i (i<5, cf<19) and ALL 4 row-frags -> acc[4][5].
// A-tile staged to LDS ONCE per pass (1 barrier); W read directly from global
// (L2-resident, each block reads each W element exactly once). K-loop has NO barriers.
#define SLDA 40
__global__ __launch_bounds__(256) void gemm_kernel(
    const ushort_t* __restrict__ A1, int lda1, int nks1,
    const ushort_t* __restrict__ W1, int ldw1,
    const ushort_t* __restrict__ A2, int lda2, int nks2,
    const ushort_t* __restrict__ W2, int ldw2,
    const float* __restrict__ bias,
    const ushort_t* __restrict__ add1, const ushort_t* __restrict__ add2,
    ushort_t* __restrict__ outB, ushort_t* __restrict__ outB2,
    float* __restrict__ outF) {
  __shared__ ushort_t sA[10 * 64 * SLDA];  // 51.2 KB (10 K-chunks of 32)
  int tid = threadIdx.x;
  int w = tid >> 6, lane = tid & 63;
  int rowbase = blockIdx.x * 64;
  f32x4 acc[4][5];
#pragma unroll
  for (int rf = 0; rf < 4; rf++)
#pragma unroll
    for (int i = 0; i < 5; i++) acc[rf][i] = (f32x4){0.f, 0.f, 0.f, 0.f};

  int strow = tid >> 2, stslot = tid & 3;
  int mrow = lane & 15;
  int koff = (lane >> 4) * 8;

  for (int pass = 0; pass < 2; pass++) {
    const ushort_t* Ap = (pass == 0) ? A1 : A2;
    const ushort_t* Wp = (pass == 0) ? W1 : W2;
    int lda = (pass == 0) ? lda1 : lda2;
    int ldw = (pass == 0) ? ldw1 : ldw2;
    int nks = (pass == 0) ? nks1 : nks2;
    if (nks == 0) continue;
    // stage full A-tile for this pass (64 rows x nks*32 cols)
    {
      int gr = rowbase + strow;
      for (int ks = 0; ks < nks; ks++) {
        uint4 val = {0u, 0u, 0u, 0u};
        if (gr < NN) val = *(const uint4*)(Ap + (long)gr * lda + ks * 32 + stslot * 8);
        *(uint4*)(&sA[((ks * 64) + strow) * SLDA + stslot * 8]) = val;
      }
    }
    __syncthreads();
#pragma unroll 5
    for (int ks = 0; ks < nks; ks++) {
      short8 af[4];
#pragma unroll
      for (int rf = 0; rf < 4; rf++)
        af[rf] = *(const short8*)(&sA[((ks * 64) + rf * 16 + mrow) * SLDA + koff]);
#pragma unroll
      for (int i = 0; i < 5; i++) {
        int cf = w + 4 * i;
        if (cf < 19) {
          short8 bfr = *(const short8*)(Wp + (long)(cf * 16 + mrow) * ldw + ks * 32 + koff);
#pragma unroll
          for (int rf = 0; rf < 4; rf++)
            acc[rf][i] = __builtin_amdgcn_mfma_f32_16x16x32_bf16(af[rf], bfr, acc[rf][i], 0, 0, 0);
        }
      }
    }
    __syncthreads();  // protect sA reuse by next pass
  }
  // epilogue: D layout col = lane&15, row = (lane>>4)*4 + reg
  int rloc = (lane >> 4) * 4;
  int cloc = lane & 15;
#pragma unroll
  for (int rf = 0; rf < 4; rf++) {
    for (int i = 0; i < 5; i++) {
      int cf = w + 4 * i;
      if (cf >= 19) continue;
      int gc = cf * 16 + cloc;
      if (gc >= DH) continue;
#pragma unroll
      for (int r = 0; r < 4; r++) {
        int gr = rowbase + rf * 16 + rloc + r;
        if (gr >= NN) continue;
        float v = acc[rf][i][r];
        if (bias) v += bias[gc];
        if (add1) v += bf2f(add1[(long)gr * LDH + gc]);
        if (add2) v += bf2f(add2[(long)gr * LDH + gc]);
        v = fmaxf(v, 0.f);
        if (outB) outB[(long)gr * LDH + gc] = f2bf(v);
        if (outB2) outB2[(long)gr * LDH + gc] = f2bf(v);
        if (outF) outF[(long)gr * DH + gc] = v;
      }
    }
  }
}

extern "C" void kernel_launch(void* const* d_in, const int* in_sizes, int n_in,
                              void* d_out, int out_size, void* d_ws, size_t ws_size,
                              hipStream_t stream) {
  const float* V   = (const float*)d_in[0];
  const float* E   = (const float*)d_in[1];
  const void*  ei  = d_in[2];
  const float* W_i = (const float*)d_in[3];
  const float* b_i = (const float*)d_in[4];
  const float* W_h = (const float*)d_in[5];
  const float* b_h = (const float*)d_in[6];
  const float* W_o = (const float*)d_in[7];
  const float* b_o = (const float*)d_in[8];
  float* out = (float*)d_out;

  char* ws = (char*)d_ws;
  size_t off = 0;
  auto alloc = [&](size_t bytes) {
    void* p = ws + off;
    off = (off + bytes + 255) & ~(size_t)255;
    return p;
  };
  ushort_t* Vbf  = (ushort_t*)alloc((size_t)NN * 160 * 2);
  ushort_t* Hb   = (ushort_t*)alloc((size_t)NN * LDH * 2);
  ushort_t* H0b  = (ushort_t*)alloc((size_t)NN * LDH * 2);
  ushort_t* Ab   = (ushort_t*)alloc((size_t)NN * LDH * 2);
  ushort_t* Cb   = (ushort_t*)alloc((size_t)NN * LDH * 2);
  ushort_t* Wib  = (ushort_t*)alloc((size_t)304 * 160 * 2);
  ushort_t* WhHb = (ushort_t*)alloc((size_t)304 * 320 * 2);
  ushort_t* WoVb = (ushort_t*)alloc((size_t)304 * 160 * 2);
  ushort_t* WoHb = (ushort_t*)alloc((size_t)304 * 320 * 2);
  float*  Esum   = (float*)alloc((size_t)NN * DE * 4);
  int* counts    = (int*)alloc((size_t)NN * 4);
  int* rp        = (int*)alloc((size_t)(NN + 4) * 4);
  int* cursor    = (int*)alloc((size_t)NN * 4);
  int* ssrc      = (int*)alloc((size_t)NE * 4);
  int* src32     = (int*)alloc((size_t)NE * 4);
  int* dst32     = (int*)alloc((size_t)NE * 4);
  int* slocal    = (int*)alloc((size_t)NN * 4);
  int* sbsums    = (int*)alloc((size_t)256 * 4);
  int* flag      = (int*)alloc(256);

  // zero-init: K-pad columns of Hb must be 0 (gather + GEMM-A reads); Esum/counts accumulate
  hipMemsetAsync(Hb, 0, (size_t)NN * LDH * 2, stream);
  hipMemsetAsync(Esum, 0, (size_t)NN * DE * 4, stream);
  hipMemsetAsync(counts, 0, (size_t)NN * 4, stream);

  // normalize edge_index to int32 src/dst regardless of on-device dtype
  detect_kernel<<<1, 256, 0, stream>>>((const int*)ei, flag);
  decode_kernel<<<(NE + 255) / 256, 256, 0, stream>>>(ei, flag, src32, dst32);

  auto conv = [&](const float* src, int sld, int coff, int rows, int cols,
                  ushort_t* dst, int dld, int drows) {
    long total = (long)drows * dld;
    convert_pad_kernel<<<(int)((total + 255) / 256), 256, 0, stream>>>(
        src, sld, coff, rows, cols, dst, dld, total);
  };
  conv(V, DV, 0, NN, DV, Vbf, 160, NN);
  conv(W_i, DV, 0, DH, DV, Wib, 160, 304);
  conv(W_h, DH + DE, 0, DH, DH, WhHb, 320, 304);
  conv(W_o, DV + DH, 0, DH, DV, WoVb, 160, 304);
  conv(W_o, DV + DH, DV, DH, DH, WoHb, 320, 304);

  esum_count_kernel<<<NE * 16 / 256, 256, 0, stream>>>(dst32, E, Esum, counts);

  // H0 = relu(V @ W_i^T + b_i) -> Hb (iteration state) and H0b (skip connection)
  gemm_kernel<<<(NN + 63) / 64, 256, 0, stream>>>(
      Vbf, 160, 5, Wib, 160, nullptr, 0, 0, nullptr, 0,
      b_i, nullptr, nullptr, Hb, H0b, nullptr);

  // parallel scan of counts -> rp / cursor
  scan1_kernel<<<(NN + 255) / 256, 256, 0, stream>>>(counts, slocal, sbsums, NN);
  scan2_kernel<<<1, 256, 0, stream>>>(sbsums, (NN + 255) / 256);
  scan3_kernel<<<(NN + 256) / 256, 256, 0, stream>>>(slocal, sbsums, rp, cursor, NN);

  fill_kernel<<<(NE + 255) / 256, 256, 0, stream>>>(src32, dst32, cursor, ssrc);
  cterm_kernel<<<dim3(2, NN), 256, 0, stream>>>(Esum, rp, W_h, b_h, Cb);

  for (int it = 0; it < 2; it++) {
    gather_kernel<<<NN / 4, 256, 0, stream>>>(Hb, rp, ssrc, Ab);
    // H = relu(H0 + A @ W_hH^T + C)   (b_h is inside C as deg*b_h)
    gemm_kernel<<<(NN + 63) / 64, 256, 0, stream>>>(
        Ab, 320, 10, WhHb, 320, nullptr, 0, 0, nullptr, 0,
        nullptr, H0b, Cb, Hb, nullptr, nullptr);
  }
  gather_kernel<<<NN / 4, 256, 0, stream>>>(Hb, rp, ssrc, Ab);
  // H_v = relu(V @ W_oV^T + M_v @ W_oH^T + b_o) -> f32 d_out
  gemm_kernel<<<(NN + 63) / 64, 256, 0, stream>>>(
      Vbf, 160, 5, WoVb, 160, Ab, 320, 10, WoHb, 320,
      b_o, nullptr, nullptr, nullptr, nullptr, out);
}

// Round 5
// 1333.991 us; speedup vs baseline: 1.0596x; 1.0596x over previous
//
#include <hip/hip_runtime.h>
#include <hip/hip_bf16.h>
#include <stdint.h>

// Problem constants (from reference)
#define NN 50000
#define NE 800000
#define DV 133
#define DE 14
#define DH 300
#define LDH 320   // padded row stride (shorts) for all node-state buffers

typedef unsigned short ushort_t;
typedef __attribute__((ext_vector_type(8))) short short8;
typedef __attribute__((ext_vector_type(4))) float f32x4;

__device__ __forceinline__ float bf2f(ushort_t u) {
  union { unsigned int i; float f; } v; v.i = ((unsigned int)u) << 16; return v.f;
}
__device__ __forceinline__ ushort_t f2bf(float f) {
  union { unsigned int i; float f; } v; v.f = f;
  unsigned int u = v.i;
  return (ushort_t)((u + 0x7fffu + ((u >> 16) & 1u)) >> 16);
}
__device__ __forceinline__ float u_lo(unsigned int u) {
  union { unsigned int i; float f; } v; v.i = u << 16; return v.f;
}
__device__ __forceinline__ float u_hi(unsigned int u) {
  union { unsigned int i; float f; } v; v.i = u & 0xffff0000u; return v.f;
}

// async global->LDS, 16B per lane; LDS dest = wave-uniform base + lane*16
__device__ __forceinline__ void gload16(const void* g, void* l) {
  __builtin_amdgcn_global_load_lds(
      (const __attribute__((address_space(1))) unsigned int*)g,
      (__attribute__((address_space(3))) unsigned int*)l, 16, 0, 0);
}

// ---------------- edge_index dtype detection (int64 vs int32) ----------------
__global__ void detect_kernel(const int* __restrict__ ei32, int* __restrict__ flag) {
  __shared__ int s_or;
  if (threadIdx.x == 0) s_or = 0;
  __syncthreads();
  int v = ei32[2 * threadIdx.x + 1] | ei32[2 * (threadIdx.x + 256) + 1] |
          ei32[2 * (threadIdx.x + 512) + 1] | ei32[2 * (threadIdx.x + 768) + 1];
  if (v) atomicOr(&s_or, 1);
  __syncthreads();
  if (threadIdx.x == 0) *flag = (s_or == 0) ? 1 : 0;
}

__global__ void decode_kernel(const void* __restrict__ ei_raw, const int* __restrict__ flag,
                              int* __restrict__ src32, int* __restrict__ dst32) {
  int e = blockIdx.x * blockDim.x + threadIdx.x;
  if (e >= NE) return;
  if (*flag) {
    const long long* p = (const long long*)ei_raw;
    src32[e] = (int)p[e];
    dst32[e] = (int)p[NE + e];
  } else {
    const int* p = (const int*)ei_raw;
    src32[e] = p[e];
    dst32[e] = p[NE + e];
  }
}

// ---------------- conversion: f32 submatrix -> zero-padded bf16 ----------------
__global__ void convert_pad_kernel(const float* __restrict__ src, int src_ld, int col_off,
                                   int rows, int cols, ushort_t* __restrict__ dst, int dst_ld,
                                   long total) {
  long gid = (long)blockIdx.x * blockDim.x + threadIdx.x;
  if (gid >= total) return;
  int r = (int)(gid / dst_ld), c = (int)(gid % dst_ld);
  float v = (r < rows && c < cols) ? src[(long)r * src_ld + col_off + c] : 0.f;
  dst[gid] = f2bf(v);
}

// ---------------- per-dst edge-feature sums + degree counts ----------------
__global__ void esum_count_kernel(const int* __restrict__ dst32, const float* __restrict__ Ef,
                                  float* __restrict__ Esum, int* __restrict__ counts) {
  int gid = blockIdx.x * blockDim.x + threadIdx.x;
  int e = gid >> 4, k = gid & 15;
  if (e >= NE) return;
  int dst = dst32[e];
  if (k < DE) atomicAdd(&Esum[dst * DE + k], Ef[(long)e * DE + k]);
  if (k == 15) atomicAdd(&counts[dst], 1);
}

// ---------------- parallel scan (3 kernels) ----------------
__global__ void scan1_kernel(const int* __restrict__ counts, int* __restrict__ local,
                             int* __restrict__ bsums, int n) {
  __shared__ int wsum[4];
  int b = blockIdx.x, t = threadIdx.x;
  int i = b * 256 + t;
  int v = (i < n) ? counts[i] : 0;
  int lane = t & 63, wid = t >> 6;
  int x = v;
#pragma unroll
  for (int d = 1; d < 64; d <<= 1) {
    int y = __shfl_up(x, d);
    if (lane >= d) x += y;
  }
  if (lane == 63) wsum[wid] = x;
  __syncthreads();
  int add = 0;
  for (int k = 0; k < wid; k++) add += wsum[k];
  int incl = x + add;
  if (i < n) local[i] = incl - v;
  if (t == 255) bsums[b] = incl;
}

__global__ void scan2_kernel(int* __restrict__ bsums, int nb) {
  __shared__ int buf[256];
  int t = threadIdx.x;
  int v = (t < nb) ? bsums[t] : 0;
  buf[t] = v;
  __syncthreads();
  for (int d = 1; d < 256; d <<= 1) {
    int a = (t >= d) ? buf[t - d] : 0;
    __syncthreads();
    buf[t] += a;
    __syncthreads();
  }
  if (t < nb) bsums[t] = buf[t] - v;  // exclusive
}

__global__ void scan3_kernel(const int* __restrict__ local, const int* __restrict__ bsums,
                             int* __restrict__ rp, int* __restrict__ cursor, int n) {
  int i = blockIdx.x * 256 + threadIdx.x;
  if (i > n) return;
  int v = (i < n) ? (local[i] + bsums[i >> 8]) : NE;
  rp[i] = v;
  if (i < n) cursor[i] = v;
}

// ---------------- CSR fill: bucket src ids by dst ----------------
__global__ void fill_kernel(const int* __restrict__ src32, const int* __restrict__ dst32,
                            int* __restrict__ cursor, int* __restrict__ ssrc) {
  int e = blockIdx.x * blockDim.x + threadIdx.x;
  if (e >= NE) return;
  int dst = dst32[e];
  int pos = atomicAdd(&cursor[dst], 1);
  ssrc[pos] = src32[e];
}

// ---------------- constant term C = Esum @ W_hE^T + deg * b_h ----------------
__global__ void cterm_kernel(const float* __restrict__ Esum, const int* __restrict__ rp,
                             const float* __restrict__ W_h, const float* __restrict__ b_h,
                             ushort_t* __restrict__ Cb) {
  int n = blockIdx.y;
  int j = blockIdx.x * blockDim.x + threadIdx.x;
  if (j >= DH) return;
  float deg = (float)(rp[n + 1] - rp[n]);
  float acc = deg * b_h[j];
#pragma unroll
  for (int k = 0; k < DE; k++) acc += Esum[n * DE + k] * W_h[j * (DH + DE) + DH + k];
  Cb[(long)n * LDH + j] = f2bf(acc);
}

// ---------------- segment-sum via CSR gather: A[n] = sum_{e:dst=n} H[src_e] ----------------
// one wave per node; row = 320 bf16 = 640B = 40 lanes x 16B
__global__ void gather_kernel(const ushort_t* __restrict__ H, const int* __restrict__ rp,
                              const int* __restrict__ ssrc, ushort_t* __restrict__ A) {
  int wave = blockIdx.x * (blockDim.x >> 6) + (threadIdx.x >> 6);
  int lane = threadIdx.x & 63;
  if (wave >= NN || lane >= 40) return;
  int start = rp[wave], end = rp[wave + 1];
  float a0 = 0, a1 = 0, a2 = 0, a3 = 0, a4 = 0, a5 = 0, a6 = 0, a7 = 0;
  const uint4* base = (const uint4*)H;  // 40 uint4 per row
  int i = start;
  for (; i + 1 < end; i += 2) {
    int s0 = ssrc[i], s1 = ssrc[i + 1];
    uint4 x = base[(long)s0 * 40 + lane];
    uint4 y = base[(long)s1 * 40 + lane];
    a0 += u_lo(x.x); a1 += u_hi(x.x); a2 += u_lo(x.y); a3 += u_hi(x.y);
    a4 += u_lo(x.z); a5 += u_hi(x.z); a6 += u_lo(x.w); a7 += u_hi(x.w);
    a0 += u_lo(y.x); a1 += u_hi(y.x); a2 += u_lo(y.y); a3 += u_hi(y.y);
    a4 += u_lo(y.z); a5 += u_hi(y.z); a6 += u_lo(y.w); a7 += u_hi(y.w);
  }
  if (i < end) {
    int s0 = ssrc[i];
    uint4 x = base[(long)s0 * 40 + lane];
    a0 += u_lo(x.x); a1 += u_hi(x.x); a2 += u_lo(x.y); a3 += u_hi(x.y);
    a4 += u_lo(x.z); a5 += u_hi(x.z); a6 += u_lo(x.w); a7 += u_hi(x.w);
  }
  uint4 o;
  o.x = (unsigned int)f2bf(a0) | ((unsigned int)f2bf(a1) << 16);
  o.y = (unsigned int)f2bf(a2) | ((unsigned int)f2bf(a3) << 16);
  o.z = (unsigned int)f2bf(a4) | ((unsigned int)f2bf(a5) << 16);
  o.w = (unsigned int)f2bf(a6) | ((unsigned int)f2bf(a7) << 16);
  ((uint4*)A)[(long)wave * 40 + lane] = o;
}

// ---------------- bf16 MFMA GEMM, 2-phase pipelined (T3 minimum recipe) ----------------
// out = relu(A1@W1^T [+ A2@W2^T] + bias + add1 + add2)
// 256 thr = 4 waves; tile 64 rows x 304 cols; wave w: col-frags cf=w+4i (i<5), all 4 row-frags.
// Per K-step (BK=32): A 64x32 (4KB) + W 304x32 (19KB) staged via global_load_lds into the
// double buffer for step s+1 WHILE computing step s; ONE __syncthreads per step (drains vmcnt).
// LDS layout: linear 16-row x 64B subtiles (chunk = 1KB = 64 lanes x 16B), with both-sides
// XOR swizzle slot' = slot ^ ((row>>1)&3): bank-start = (row&1)*16 + slot'*4 -> 8 distinct
// starts x 2 lanes per 16-lane group = conflict-free ds_read_b128 (2-way is free, m136).
__global__ __launch_bounds__(256) void gemm_kernel(
    const ushort_t* __restrict__ A1, int lda1, int nks1,
    const ushort_t* __restrict__ W1, int ldw1,
    const ushort_t* __restrict__ A2, int lda2, int nks2,
    const ushort_t* __restrict__ W2, int ldw2,
    const float* __restrict__ bias,
    const ushort_t* __restrict__ add1, const ushort_t* __restrict__ add2,
    ushort_t* __restrict__ outB, ushort_t* __restrict__ outB2,
    float* __restrict__ outF) {
  __shared__ ushort_t sA[2][2048];   // 2 x 4KB   (64 rows x 32)
  __shared__ ushort_t sW[2][9728];   // 2 x 19KB  (304 rows x 32)
  int tid = threadIdx.x;
  int w = tid >> 6, lane = tid & 63;
  int rowbase = blockIdx.x * 64;
  int nsteps = nks1 + nks2;

  f32x4 acc[4][5];
#pragma unroll
  for (int rf = 0; rf < 4; rf++)
#pragma unroll
    for (int i = 0; i < 5; i++) acc[rf][i] = (f32x4){0.f, 0.f, 0.f, 0.f};

  // staging lane mapping: 16B per lane; chunk = 16 rows; row-in-chunk = lane>>2, slot = lane&3
  int rsub = lane >> 2, slot = lane & 3;
  int sgo = (slot ^ ((rsub >> 1) & 3)) * 8;  // pre-swizzled global k-offset (shorts)
  // compute lane mapping
  int mrow = lane & 15, sub = lane >> 4;
  int ssw = (sub ^ ((mrow >> 1) & 3)) * 8;   // swizzled LDS k-offset (shorts)

  auto stage = [&](int s, int b) {
    int pass = (s >= nks1);
    const ushort_t* Ap = pass ? A2 : A1;
    const ushort_t* Wp = pass ? W2 : W1;
    int lda = pass ? lda2 : lda1;
    int ldw = pass ? ldw2 : ldw1;
    int ks = pass ? (s - nks1) : s;
    // A chunk w: rows [w*16, w*16+16)
    {
      int gr = rowbase + w * 16 + rsub;
      if (gr < NN)
        gload16(Ap + (long)gr * lda + ks * 32 + sgo, &sA[b][w * 512]);
    }
    // W chunks w, w+4, ..., (19 total)
#pragma unroll
    for (int i = 0; i < 5; i++) {
      int c = w + 4 * i;
      if (c < 19) {
        int row = c * 16 + rsub;
        gload16(Wp + (long)row * ldw + ks * 32 + sgo, &sW[b][c * 512]);
      }
    }
  };

  stage(0, 0);
  __syncthreads();
  for (int s = 0; s < nsteps; s++) {
    int b = s & 1;
    if (s + 1 < nsteps) stage(s + 1, b ^ 1);  // async loads fly under the MFMAs
    short8 af[4];
#pragma unroll
    for (int rf = 0; rf < 4; rf++)
      af[rf] = *(const short8*)(&sA[b][(rf * 16 + mrow) * 32 + ssw]);
#pragma unroll
    for (int i = 0; i < 5; i++) {
      int cf = w + 4 * i;
      if (cf < 19) {
        short8 bfr = *(const short8*)(&sW[b][(cf * 16 + mrow) * 32 + ssw]);
#pragma unroll
        for (int rf = 0; rf < 4; rf++)
          acc[rf][i] = __builtin_amdgcn_mfma_f32_16x16x32_bf16(af[rf], bfr, acc[rf][i], 0, 0, 0);
      }
    }
    __syncthreads();  // drains vmcnt(0)+lgkmcnt(0): next buffer ready, this one reusable
  }

  // epilogue: D layout col = lane&15, row = (lane>>4)*4 + reg
  int rloc = (lane >> 4) * 4;
  int cloc = lane & 15;
#pragma unroll
  for (int rf = 0; rf < 4; rf++) {
    for (int i = 0; i < 5; i++) {
      int cf = w + 4 * i;
      if (cf >= 19) continue;
      int gc = cf * 16 + cloc;
      if (gc >= DH) continue;
#pragma unroll
      for (int r = 0; r < 4; r++) {
        int gr = rowbase + rf * 16 + rloc + r;
        if (gr >= NN) continue;
        float v = acc[rf][i][r];
        if (bias) v += bias[gc];
        if (add1) v += bf2f(add1[(long)gr * LDH + gc]);
        if (add2) v += bf2f(add2[(long)gr * LDH + gc]);
        v = fmaxf(v, 0.f);
        if (outB) outB[(long)gr * LDH + gc] = f2bf(v);
        if (outB2) outB2[(long)gr * LDH + gc] = f2bf(v);
        if (outF) outF[(long)gr * DH + gc] = v;
      }
    }
  }
}

extern "C" void kernel_launch(void* const* d_in, const int* in_sizes, int n_in,
                              void* d_out, int out_size, void* d_ws, size_t ws_size,
                              hipStream_t stream) {
  const float* V   = (const float*)d_in[0];
  const float* E   = (const float*)d_in[1];
  const void*  ei  = d_in[2];
  const float* W_i = (const float*)d_in[3];
  const float* b_i = (const float*)d_in[4];
  const float* W_h = (const float*)d_in[5];
  const float* b_h = (const float*)d_in[6];
  const float* W_o = (const float*)d_in[7];
  const float* b_o = (const float*)d_in[8];
  float* out = (float*)d_out;

  char* ws = (char*)d_ws;
  size_t off = 0;
  auto alloc = [&](size_t bytes) {
    void* p = ws + off;
    off = (off + bytes + 255) & ~(size_t)255;
    return p;
  };
  ushort_t* Vbf  = (ushort_t*)alloc((size_t)NN * 160 * 2);
  ushort_t* Hb   = (ushort_t*)alloc((size_t)NN * LDH * 2);
  ushort_t* H0b  = (ushort_t*)alloc((size_t)NN * LDH * 2);
  ushort_t* Ab   = (ushort_t*)alloc((size_t)NN * LDH * 2);
  ushort_t* Cb   = (ushort_t*)alloc((size_t)NN * LDH * 2);
  ushort_t* Wib  = (ushort_t*)alloc((size_t)304 * 160 * 2);
  ushort_t* WhHb = (ushort_t*)alloc((size_t)304 * 320 * 2);
  ushort_t* WoVb = (ushort_t*)alloc((size_t)304 * 160 * 2);
  ushort_t* WoHb = (ushort_t*)alloc((size_t)304 * 320 * 2);
  float*  Esum   = (float*)alloc((size_t)NN * DE * 4);
  int* counts    = (int*)alloc((size_t)NN * 4);
  int* rp        = (int*)alloc((size_t)(NN + 4) * 4);
  int* cursor    = (int*)alloc((size_t)NN * 4);
  int* ssrc      = (int*)alloc((size_t)NE * 4);
  int* src32     = (int*)alloc((size_t)NE * 4);
  int* dst32     = (int*)alloc((size_t)NE * 4);
  int* slocal    = (int*)alloc((size_t)NN * 4);
  int* sbsums    = (int*)alloc((size_t)256 * 4);
  int* flag      = (int*)alloc(256);

  // zero-init: K-pad columns of Hb must be 0 (gather + GEMM-A reads); Esum/counts accumulate
  hipMemsetAsync(Hb, 0, (size_t)NN * LDH * 2, stream);
  hipMemsetAsync(Esum, 0, (size_t)NN * DE * 4, stream);
  hipMemsetAsync(counts, 0, (size_t)NN * 4, stream);

  // normalize edge_index to int32 src/dst regardless of on-device dtype
  detect_kernel<<<1, 256, 0, stream>>>((const int*)ei, flag);
  decode_kernel<<<(NE + 255) / 256, 256, 0, stream>>>(ei, flag, src32, dst32);

  auto conv = [&](const float* src, int sld, int coff, int rows, int cols,
                  ushort_t* dst, int dld, int drows) {
    long total = (long)drows * dld;
    convert_pad_kernel<<<(int)((total + 255) / 256), 256, 0, stream>>>(
        src, sld, coff, rows, cols, dst, dld, total);
  };
  conv(V, DV, 0, NN, DV, Vbf, 160, NN);
  conv(W_i, DV, 0, DH, DV, Wib, 160, 304);
  conv(W_h, DH + DE, 0, DH, DH, WhHb, 320, 304);
  conv(W_o, DV + DH, 0, DH, DV, WoVb, 160, 304);
  conv(W_o, DV + DH, DV, DH, DH, WoHb, 320, 304);

  esum_count_kernel<<<NE * 16 / 256, 256, 0, stream>>>(dst32, E, Esum, counts);

  // H0 = relu(V @ W_i^T + b_i) -> Hb (iteration state) and H0b (skip connection)
  gemm_kernel<<<(NN + 63) / 64, 256, 0, stream>>>(
      Vbf, 160, 5, Wib, 160, nullptr, 0, 0, nullptr, 0,
      b_i, nullptr, nullptr, Hb, H0b, nullptr);

  // parallel scan of counts -> rp / cursor
  scan1_kernel<<<(NN + 255) / 256, 256, 0, stream>>>(counts, slocal, sbsums, NN);
  scan2_kernel<<<1, 256, 0, stream>>>(sbsums, (NN + 255) / 256);
  scan3_kernel<<<(NN + 256) / 256, 256, 0, stream>>>(slocal, sbsums, rp, cursor, NN);

  fill_kernel<<<(NE + 255) / 256, 256, 0, stream>>>(src32, dst32, cursor, ssrc);
  cterm_kernel<<<dim3(2, NN), 256, 0, stream>>>(Esum, rp, W_h, b_h, Cb);

  for (int it = 0; it < 2; it++) {
    gather_kernel<<<NN / 4, 256, 0, stream>>>(Hb, rp, ssrc, Ab);
    // H = relu(H0 + A @ W_hH^T + C)   (b_h is inside C as deg*b_h)
    gemm_kernel<<<(NN + 63) / 64, 256, 0, stream>>>(
        Ab, 320, 10, WhHb, 320, nullptr, 0, 0, nullptr, 0,
        nullptr, H0b, Cb, Hb, nullptr, nullptr);
  }
  gather_kernel<<<NN / 4, 256, 0, stream>>>(Hb, rp, ssrc, Ab);
  // H_v = relu(V @ W_oV^T + M_v @ W_oH^T + b_o) -> f32 d_out
  gemm_kernel<<<(NN + 63) / 64, 256, 0, stream>>>(
      Vbf, 160, 5, WoVb, 160, Ab, 320, 10, WoHb, 320,
      b_o, nullptr, nullptr, nullptr, nullptr, out);
}

// Round 8
// 829.243 us; speedup vs baseline: 1.7045x; 1.6087x over previous
//
#include <hip/hip_runtime.h>
#include <hip/hip_bf16.h>
#include <stdint.h>

// Problem constants (from reference)
#define NN 50000
#define NE 800000
#define DV 133
#define DE 14
#define DH 300
#define LDH 320   // padded row stride (shorts) for all node-state buffers

typedef unsigned short ushort_t;
typedef __attribute__((ext_vector_type(8))) short short8;
typedef __attribute__((ext_vector_type(4))) float f32x4;

__device__ __forceinline__ float bf2f(ushort_t u) {
  union { unsigned int i; float f; } v; v.i = ((unsigned int)u) << 16; return v.f;
}
__device__ __forceinline__ ushort_t f2bf(float f) {
  union { unsigned int i; float f; } v; v.f = f;
  unsigned int u = v.i;
  return (ushort_t)((u + 0x7fffu + ((u >> 16) & 1u)) >> 16);
}
__device__ __forceinline__ float u_lo(unsigned int u) {
  union { unsigned int i; float f; } v; v.i = u << 16; return v.f;
}
__device__ __forceinline__ float u_hi(unsigned int u) {
  union { unsigned int i; float f; } v; v.i = u & 0xffff0000u; return v.f;
}

// async global->LDS, 16B per lane; LDS dest = wave-uniform base + lane*16
__device__ __forceinline__ void gload16(const void* g, void* l) {
  __builtin_amdgcn_global_load_lds(
      (const __attribute__((address_space(1))) unsigned int*)g,
      (__attribute__((address_space(3))) unsigned int*)l, 16, 0, 0);
}

// ---------------- edge_index dtype detection (int64 vs int32) ----------------
__global__ void detect_kernel(const int* __restrict__ ei32, int* __restrict__ flag) {
  __shared__ int s_or;
  if (threadIdx.x == 0) s_or = 0;
  __syncthreads();
  int v = ei32[2 * threadIdx.x + 1] | ei32[2 * (threadIdx.x + 256) + 1] |
          ei32[2 * (threadIdx.x + 512) + 1] | ei32[2 * (threadIdx.x + 768) + 1];
  if (v) atomicOr(&s_or, 1);
  __syncthreads();
  if (threadIdx.x == 0) *flag = (s_or == 0) ? 1 : 0;
}

__global__ void decode_kernel(const void* __restrict__ ei_raw, const int* __restrict__ flag,
                              int* __restrict__ src32, int* __restrict__ dst32) {
  int e = blockIdx.x * blockDim.x + threadIdx.x;
  if (e >= NE) return;
  if (*flag) {
    const long long* p = (const long long*)ei_raw;
    src32[e] = (int)p[e];
    dst32[e] = (int)p[NE + e];
  } else {
    const int* p = (const int*)ei_raw;
    src32[e] = p[e];
    dst32[e] = p[NE + e];
  }
}

// ---------------- conversion: f32 submatrix -> zero-padded bf16 ----------------
__global__ void convert_pad_kernel(const float* __restrict__ src, int src_ld, int col_off,
                                   int rows, int cols, ushort_t* __restrict__ dst, int dst_ld,
                                   long total) {
  long gid = (long)blockIdx.x * blockDim.x + threadIdx.x;
  if (gid >= total) return;
  int r = (int)(gid / dst_ld), c = (int)(gid % dst_ld);
  float v = (r < rows && c < cols) ? src[(long)r * src_ld + col_off + c] : 0.f;
  dst[gid] = f2bf(v);
}

// ---------------- per-dst edge-feature sums + degree counts ----------------
__global__ void esum_count_kernel(const int* __restrict__ dst32, const float* __restrict__ Ef,
                                  float* __restrict__ Esum, int* __restrict__ counts) {
  int gid = blockIdx.x * blockDim.x + threadIdx.x;
  int e = gid >> 4, k = gid & 15;
  if (e >= NE) return;
  int dst = dst32[e];
  if (k < DE) atomicAdd(&Esum[dst * DE + k], Ef[(long)e * DE + k]);
  if (k == 15) atomicAdd(&counts[dst], 1);
}

// ---------------- parallel scan (3 kernels) ----------------
__global__ void scan1_kernel(const int* __restrict__ counts, int* __restrict__ local,
                             int* __restrict__ bsums, int n) {
  __shared__ int wsum[4];
  int b = blockIdx.x, t = threadIdx.x;
  int i = b * 256 + t;
  int v = (i < n) ? counts[i] : 0;
  int lane = t & 63, wid = t >> 6;
  int x = v;
#pragma unroll
  for (int d = 1; d < 64; d <<= 1) {
    int y = __shfl_up(x, d);
    if (lane >= d) x += y;
  }
  if (lane == 63) wsum[wid] = x;
  __syncthreads();
  int add = 0;
  for (int k = 0; k < wid; k++) add += wsum[k];
  int incl = x + add;
  if (i < n) local[i] = incl - v;
  if (t == 255) bsums[b] = incl;
}

__global__ void scan2_kernel(int* __restrict__ bsums, int nb) {
  __shared__ int buf[256];
  int t = threadIdx.x;
  int v = (t < nb) ? bsums[t] : 0;
  buf[t] = v;
  __syncthreads();
  for (int d = 1; d < 256; d <<= 1) {
    int a = (t >= d) ? buf[t - d] : 0;
    __syncthreads();
    buf[t] += a;
    __syncthreads();
  }
  if (t < nb) bsums[t] = buf[t] - v;  // exclusive
}

__global__ void scan3_kernel(const int* __restrict__ local, const int* __restrict__ bsums,
                             int* __restrict__ rp, int* __restrict__ cursor, int n) {
  int i = blockIdx.x * 256 + threadIdx.x;
  if (i > n) return;
  int v = (i < n) ? (local[i] + bsums[i >> 8]) : NE;
  rp[i] = v;
  if (i < n) cursor[i] = v;
}

// ---------------- CSR fill: bucket src ids by dst ----------------
__global__ void fill_kernel(const int* __restrict__ src32, const int* __restrict__ dst32,
                            int* __restrict__ cursor, int* __restrict__ ssrc) {
  int e = blockIdx.x * blockDim.x + threadIdx.x;
  if (e >= NE) return;
  int dst = dst32[e];
  int pos = atomicAdd(&cursor[dst], 1);
  ssrc[pos] = src32[e];
}

// ---------------- S = H0 + Esum @ W_hE^T + deg * b_h  (iteration-invariant) ----------------
__global__ void cterm_kernel(const float* __restrict__ Esum, const int* __restrict__ rp,
                             const float* __restrict__ W_h, const float* __restrict__ b_h,
                             const ushort_t* __restrict__ H0, ushort_t* __restrict__ Sb) {
  int n = blockIdx.y;
  int j = blockIdx.x * blockDim.x + threadIdx.x;
  if (j >= DH) return;
  float deg = (float)(rp[n + 1] - rp[n]);
  float acc = deg * b_h[j] + bf2f(H0[(long)n * LDH + j]);
#pragma unroll
  for (int k = 0; k < DE; k++) acc += Esum[n * DE + k] * W_h[j * (DH + DE) + DH + k];
  Sb[(long)n * LDH + j] = f2bf(acc);
}

// ---------------- segment-sum via CSR gather: A[n] = sum_{e:dst=n} H[src_e] ----------------
// one wave per node; row = 320 bf16 = 640B = 40 lanes x 16B
__global__ void gather_kernel(const ushort_t* __restrict__ H, const int* __restrict__ rp,
                              const int* __restrict__ ssrc, ushort_t* __restrict__ A) {
  int wave = blockIdx.x * (blockDim.x >> 6) + (threadIdx.x >> 6);
  int lane = threadIdx.x & 63;
  if (wave >= NN || lane >= 40) return;
  int start = rp[wave], end = rp[wave + 1];
  float a0 = 0, a1 = 0, a2 = 0, a3 = 0, a4 = 0, a5 = 0, a6 = 0, a7 = 0;
  const uint4* base = (const uint4*)H;  // 40 uint4 per row
  int i = start;
  for (; i + 1 < end; i += 2) {
    int s0 = ssrc[i], s1 = ssrc[i + 1];
    uint4 x = base[(long)s0 * 40 + lane];
    uint4 y = base[(long)s1 * 40 + lane];
    a0 += u_lo(x.x); a1 += u_hi(x.x); a2 += u_lo(x.y); a3 += u_hi(x.y);
    a4 += u_lo(x.z); a5 += u_hi(x.z); a6 += u_lo(x.w); a7 += u_hi(x.w);
    a0 += u_lo(y.x); a1 += u_hi(y.x); a2 += u_lo(y.y); a3 += u_hi(y.y);
    a4 += u_lo(y.z); a5 += u_hi(y.z); a6 += u_lo(y.w); a7 += u_hi(y.w);
  }
  if (i < end) {
    int s0 = ssrc[i];
    uint4 x = base[(long)s0 * 40 + lane];
    a0 += u_lo(x.x); a1 += u_hi(x.x); a2 += u_lo(x.y); a3 += u_hi(x.y);
    a4 += u_lo(x.z); a5 += u_hi(x.z); a6 += u_lo(x.w); a7 += u_hi(x.w);
  }
  uint4 o;
  o.x = (unsigned int)f2bf(a0) | ((unsigned int)f2bf(a1) << 16);
  o.y = (unsigned int)f2bf(a2) | ((unsigned int)f2bf(a3) << 16);
  o.z = (unsigned int)f2bf(a4) | ((unsigned int)f2bf(a5) << 16);
  o.w = (unsigned int)f2bf(a6) | ((unsigned int)f2bf(a7) << 16);
  ((uint4*)A)[(long)wave * 40 + lane] = o;
}

// ---------------- bf16 MFMA GEMM, depth-2 prefetch, counted vmcnt (T3+T4) ----------------
// out = relu(A1@W1^T [+ A2@W2^T] + bias + add1)
// 512 thr = 8 waves; tile 64 rows x 304 cols. Wave w: col-frags cf=w+8i (i<3, cf<19),
// all 4 row-frags -> acc[4][3]. Per K-step (BK=32): 24 chunks of 1KB (4 A + 19 W + 1 dummy),
// 3 per wave -> uniform vmcnt counts. Triple-buffered LDS, loads for step s issued at s-2,
// waited with s_waitcnt vmcnt(3) (NEVER 0 in steady state) + raw s_barrier.
// Swizzle (round-5-verified, bank-conflict=0): slot' = slot ^ ((row>>1)&3), both sides.
__global__ __launch_bounds__(512) void gemm_kernel(
    const ushort_t* __restrict__ A1, int lda1, int nks1,
    const ushort_t* __restrict__ W1, int ldw1,
    const ushort_t* __restrict__ A2, int lda2, int nks2,
    const ushort_t* __restrict__ W2, int ldw2,
    const float* __restrict__ bias,
    const ushort_t* __restrict__ add1,
    ushort_t* __restrict__ outB,
    float* __restrict__ outF) {
  __shared__ ushort_t sA[3][2048];    // 3 x 4KB   (4 chunks x 512 shorts)
  __shared__ ushort_t sW[3][10240];   // 3 x 20KB  (20 chunks x 512 shorts)
  int tid = threadIdx.x;
  int w = tid >> 6, lane = tid & 63;
  int rowbase = blockIdx.x * 64;
  int nsteps = nks1 + nks2;

  f32x4 acc[4][3];
#pragma unroll
  for (int rf = 0; rf < 4; rf++)
#pragma unroll
    for (int i = 0; i < 3; i++) acc[rf][i] = (f32x4){0.f, 0.f, 0.f, 0.f};

  // staging lane mapping: 16B/lane; chunk = 16 rows x 64B; row-in-chunk = lane>>2, slot = lane&3
  int rsub = lane >> 2, slot = lane & 3;
  int sgo = (slot ^ ((rsub >> 1) & 3)) * 8;  // pre-swizzled global k-offset (shorts)
  // compute lane mapping
  int mrow = lane & 15, sub = lane >> 4;
  int ssw = (sub ^ ((mrow >> 1) & 3)) * 8;   // swizzled LDS k-offset (shorts)

  auto stage = [&](int s, int b) {
    int pass = (s >= nks1) ? 1 : 0;
    const ushort_t* Ap = pass ? A2 : A1;
    const ushort_t* Wp = pass ? W2 : W1;
    int lda = pass ? lda2 : lda1;
    int ldw = pass ? ldw2 : ldw1;
    int ks = pass ? (s - nks1) : s;
#pragma unroll
    for (int j = 0; j < 3; j++) {
      int c = w + 8 * j;
      if (c < 4) {                       // A chunk c: rows [c*16, c*16+16)
        int gr = rowbase + c * 16 + rsub;
        if (gr >= NN) gr = NN - 1;       // clamp (keeps vmcnt counts uniform)
        gload16(Ap + (long)gr * lda + ks * 32 + sgo, &sA[b][c * 512]);
      } else if (c < 23) {               // W chunk c-4: rows [(c-4)*16, ...+16)
        int row = (c - 4) * 16 + rsub;
        gload16(Wp + (long)row * ldw + ks * 32 + sgo, &sW[b][(c - 4) * 512]);
      } else {                           // dummy (uniform count): reload into unused slot 19
        int row = 288 + rsub;
        gload16(Wp + (long)row * ldw + ks * 32 + sgo, &sW[b][19 * 512]);
      }
    }
  };

  stage(0, 0);
  stage(1, 1);
  for (int s = 0; s < nsteps; s++) {
    int b = s % 3;
    if (s == nsteps - 1)
      asm volatile("s_waitcnt vmcnt(0)" ::: "memory");
    else
      asm volatile("s_waitcnt vmcnt(3)" ::: "memory");  // step-s loads (oldest) done
    __builtin_amdgcn_s_barrier();
    if (s + 2 < nsteps) stage(s + 2, (s + 2) % 3);      // issue early, land in 2 steps
    short8 af[4];
#pragma unroll
    for (int rf = 0; rf < 4; rf++)
      af[rf] = *(const short8*)(&sA[b][(rf * 16 + mrow) * 32 + ssw]);
#pragma unroll
    for (int i = 0; i < 3; i++) {
      int cf = w + 8 * i;
      if (cf < 19) {
        short8 bfr = *(const short8*)(&sW[b][(cf * 16 + mrow) * 32 + ssw]);
#pragma unroll
        for (int rf = 0; rf < 4; rf++)
          acc[rf][i] = __builtin_amdgcn_mfma_f32_16x16x32_bf16(af[rf], bfr, acc[rf][i], 0, 0, 0);
      }
    }
  }

  // ---------- epilogue: acc -> bf16 LDS bounce -> coalesced vector RMW ----------
  __syncthreads();                       // all ds_reads retired; reuse sW as bounce
  ushort_t* bounce = &sW[0][0];          // 64 x 304 shorts = 38.9KB (spans sW[0..1])
  int rloc = (lane >> 4) * 4;
  int cloc = lane & 15;
#pragma unroll
  for (int i = 0; i < 3; i++) {
    int cf = w + 8 * i;
    if (cf >= 19) continue;
    int col = cf * 16 + cloc;
#pragma unroll
    for (int rf = 0; rf < 4; rf++)
#pragma unroll
      for (int r = 0; r < 4; r++)
        bounce[(rf * 16 + rloc + r) * 304 + col] = f2bf(acc[rf][i][r]);
  }
  __syncthreads();
  for (int u = tid; u < 64 * 38; u += 512) {
    int rrow = u / 38, co = (u % 38) * 8;
    int gr = rowbase + rrow;
    if (gr >= NN) continue;
    short8 m = *(const short8*)(&bounce[rrow * 304 + co]);
    float v[8];
#pragma unroll
    for (int j = 0; j < 8; j++) v[j] = bf2f((ushort_t)m[j]);
    if (bias) {
#pragma unroll
      for (int j = 0; j < 8; j++) { int gc = co + j; if (gc < DH) v[j] += bias[gc]; }
    }
    if (add1) {
      short8 a = *(const short8*)(add1 + (long)gr * LDH + co);
#pragma unroll
      for (int j = 0; j < 8; j++) v[j] += bf2f((ushort_t)a[j]);
    }
#pragma unroll
    for (int j = 0; j < 8; j++) v[j] = fmaxf(v[j], 0.f);
    if (outB) {
      short8 o;
#pragma unroll
      for (int j = 0; j < 8; j++) o[j] = (short)f2bf(v[j]);
      *(short8*)(outB + (long)gr * LDH + co) = o;
    }
    if (outF) {
#pragma unroll
      for (int j = 0; j < 8; j++) { int gc = co + j; if (gc < DH) outF[(long)gr * DH + gc] = v[j]; }
    }
  }
}

extern "C" void kernel_launch(void* const* d_in, const int* in_sizes, int n_in,
                              void* d_out, int out_size, void* d_ws, size_t ws_size,
                              hipStream_t stream) {
  const float* V   = (const float*)d_in[0];
  const float* E   = (const float*)d_in[1];
  const void*  ei  = d_in[2];
  const float* W_i = (const float*)d_in[3];
  const float* b_i = (const float*)d_in[4];
  const float* W_h = (const float*)d_in[5];
  const float* b_h = (const float*)d_in[6];
  const float* W_o = (const float*)d_in[7];
  const float* b_o = (const float*)d_in[8];
  float* out = (float*)d_out;

  char* ws = (char*)d_ws;
  size_t off = 0;
  auto alloc = [&](size_t bytes) {
    void* p = ws + off;
    off = (off + bytes + 255) & ~(size_t)255;
    return p;
  };
  ushort_t* Vbf  = (ushort_t*)alloc((size_t)NN * 160 * 2);
  ushort_t* Hb   = (ushort_t*)alloc((size_t)NN * LDH * 2);
  ushort_t* Ab   = (ushort_t*)alloc((size_t)NN * LDH * 2);
  ushort_t* Sb   = (ushort_t*)alloc((size_t)NN * LDH * 2);
  ushort_t* Wib  = (ushort_t*)alloc((size_t)304 * 160 * 2);
  ushort_t* WhHb = (ushort_t*)alloc((size_t)304 * 320 * 2);
  ushort_t* WoVb = (ushort_t*)alloc((size_t)304 * 160 * 2);
  ushort_t* WoHb = (ushort_t*)alloc((size_t)304 * 320 * 2);
  float*  Esum   = (float*)alloc((size_t)NN * DE * 4);
  int* counts    = (int*)alloc((size_t)NN * 4);
  int* rp        = (int*)alloc((size_t)(NN + 4) * 4);
  int* cursor    = (int*)alloc((size_t)NN * 4);
  int* ssrc      = (int*)alloc((size_t)NE * 4);
  int* src32     = (int*)alloc((size_t)NE * 4);
  int* dst32     = (int*)alloc((size_t)NE * 4);
  int* slocal    = (int*)alloc((size_t)NN * 4);
  int* sbsums    = (int*)alloc((size_t)256 * 4);
  int* flag      = (int*)alloc(256);

  // zero-init: K-pad columns of Hb must be 0 (gather + GEMM-A reads); Esum/counts accumulate
  hipMemsetAsync(Hb, 0, (size_t)NN * LDH * 2, stream);
  hipMemsetAsync(Esum, 0, (size_t)NN * DE * 4, stream);
  hipMemsetAsync(counts, 0, (size_t)NN * 4, stream);

  // normalize edge_index to int32 src/dst regardless of on-device dtype
  detect_kernel<<<1, 256, 0, stream>>>((const int*)ei, flag);
  decode_kernel<<<(NE + 255) / 256, 256, 0, stream>>>(ei, flag, src32, dst32);

  auto conv = [&](const float* src, int sld, int coff, int rows, int cols,
                  ushort_t* dst, int dld, int drows) {
    long total = (long)drows * dld;
    convert_pad_kernel<<<(int)((total + 255) / 256), 256, 0, stream>>>(
        src, sld, coff, rows, cols, dst, dld, total);
  };
  conv(V, DV, 0, NN, DV, Vbf, 160, NN);
  conv(W_i, DV, 0, DH, DV, Wib, 160, 304);
  conv(W_h, DH + DE, 0, DH, DH, WhHb, 320, 304);
  conv(W_o, DV + DH, 0, DH, DV, WoVb, 160, 304);
  conv(W_o, DV + DH, DV, DH, DH, WoHb, 320, 304);

  esum_count_kernel<<<NE * 16 / 256, 256, 0, stream>>>(dst32, E, Esum, counts);

  // H0 = relu(V @ W_i^T + b_i) -> Hb (iteration state; also read by cterm as H0)
  gemm_kernel<<<(NN + 63) / 64, 512, 0, stream>>>(
      Vbf, 160, 5, Wib, 160, nullptr, 0, 0, nullptr, 0,
      b_i, nullptr, Hb, nullptr);

  // parallel scan of counts -> rp / cursor
  scan1_kernel<<<(NN + 255) / 256, 256, 0, stream>>>(counts, slocal, sbsums, NN);
  scan2_kernel<<<1, 256, 0, stream>>>(sbsums, (NN + 255) / 256);
  scan3_kernel<<<(NN + 256) / 256, 256, 0, stream>>>(slocal, sbsums, rp, cursor, NN);

  fill_kernel<<<(NE + 255) / 256, 256, 0, stream>>>(src32, dst32, cursor, ssrc);
  // S = H0 + Esum@W_hE^T + deg*b_h   (reads Hb == H0 here)
  cterm_kernel<<<dim3(2, NN), 256, 0, stream>>>(Esum, rp, W_h, b_h, Hb, Sb);

  for (int it = 0; it < 2; it++) {
    gather_kernel<<<NN / 4, 256, 0, stream>>>(Hb, rp, ssrc, Ab);
    // H = relu(S + A @ W_hH^T)
    gemm_kernel<<<(NN + 63) / 64, 512, 0, stream>>>(
        Ab, 320, 10, WhHb, 320, nullptr, 0, 0, nullptr, 0,
        nullptr, Sb, Hb, nullptr);
  }
  gather_kernel<<<NN / 4, 256, 0, stream>>>(Hb, rp, ssrc, Ab);
  // H_v = relu(V @ W_oV^T + M_v @ W_oH^T + b_o) -> f32 d_out
  gemm_kernel<<<(NN + 63) / 64, 512, 0, stream>>>(
      Vbf, 160, 5, WoVb, 160, Ab, 320, 10, WoHb, 320,
      b_o, nullptr, nullptr, out);
}

// Round 9
// 728.419 us; speedup vs baseline: 1.9404x; 1.1384x over previous
//
#include <hip/hip_runtime.h>
#include <hip/hip_bf16.h>
#include <stdint.h>

// Problem constants (from reference)
#define NN 50000
#define NE 800000
#define DV 133
#define DE 14
#define DH 300
#define LDH 320   // padded row stride (shorts) for all node-state buffers

typedef unsigned short ushort_t;
typedef __attribute__((ext_vector_type(8))) short short8;
typedef __attribute__((ext_vector_type(4))) float f32x4;

__device__ __forceinline__ float bf2f(ushort_t u) {
  union { unsigned int i; float f; } v; v.i = ((unsigned int)u) << 16; return v.f;
}
__device__ __forceinline__ ushort_t f2bf(float f) {
  union { unsigned int i; float f; } v; v.f = f;
  unsigned int u = v.i;
  return (ushort_t)((u + 0x7fffu + ((u >> 16) & 1u)) >> 16);
}
__device__ __forceinline__ float u_lo(unsigned int u) {
  union { unsigned int i; float f; } v; v.i = u << 16; return v.f;
}
__device__ __forceinline__ float u_hi(unsigned int u) {
  union { unsigned int i; float f; } v; v.i = u & 0xffff0000u; return v.f;
}

// async global->LDS, 16B per lane; LDS dest = wave-uniform base + lane*16
__device__ __forceinline__ void gload16(const void* g, void* l) {
  __builtin_amdgcn_global_load_lds(
      (const __attribute__((address_space(1))) unsigned int*)g,
      (__attribute__((address_space(3))) unsigned int*)l, 16, 0, 0);
}

// ---------------- edge_index dtype detection (int64 vs int32) ----------------
__global__ void detect_kernel(const int* __restrict__ ei32, int* __restrict__ flag) {
  __shared__ int s_or;
  if (threadIdx.x == 0) s_or = 0;
  __syncthreads();
  int v = ei32[2 * threadIdx.x + 1] | ei32[2 * (threadIdx.x + 256) + 1] |
          ei32[2 * (threadIdx.x + 512) + 1] | ei32[2 * (threadIdx.x + 768) + 1];
  if (v) atomicOr(&s_or, 1);
  __syncthreads();
  if (threadIdx.x == 0) *flag = (s_or == 0) ? 1 : 0;
}

__global__ void decode_kernel(const void* __restrict__ ei_raw, const int* __restrict__ flag,
                              int* __restrict__ src32, int* __restrict__ dst32) {
  int e = blockIdx.x * blockDim.x + threadIdx.x;
  if (e >= NE) return;
  if (*flag) {
    const long long* p = (const long long*)ei_raw;
    src32[e] = (int)p[e];
    dst32[e] = (int)p[NE + e];
  } else {
    const int* p = (const int*)ei_raw;
    src32[e] = p[e];
    dst32[e] = p[NE + e];
  }
}

// ---------------- conversion: f32 submatrix -> zero-padded bf16 ----------------
__global__ void convert_pad_kernel(const float* __restrict__ src, int src_ld, int col_off,
                                   int rows, int cols, ushort_t* __restrict__ dst, int dst_ld,
                                   long total) {
  long gid = (long)blockIdx.x * blockDim.x + threadIdx.x;
  if (gid >= total) return;
  int r = (int)(gid / dst_ld), c = (int)(gid % dst_ld);
  float v = (r < rows && c < cols) ? src[(long)r * src_ld + col_off + c] : 0.f;
  dst[gid] = f2bf(v);
}

// ---------------- per-dst edge-feature sums + degree counts ----------------
__global__ void esum_count_kernel(const int* __restrict__ dst32, const float* __restrict__ Ef,
                                  float* __restrict__ Esum, int* __restrict__ counts) {
  int gid = blockIdx.x * blockDim.x + threadIdx.x;
  int e = gid >> 4, k = gid & 15;
  if (e >= NE) return;
  int dst = dst32[e];
  if (k < DE) atomicAdd(&Esum[dst * DE + k], Ef[(long)e * DE + k]);
  if (k == 15) atomicAdd(&counts[dst], 1);
}

// ---------------- parallel scan (3 kernels) ----------------
__global__ void scan1_kernel(const int* __restrict__ counts, int* __restrict__ local,
                             int* __restrict__ bsums, int n) {
  __shared__ int wsum[4];
  int b = blockIdx.x, t = threadIdx.x;
  int i = b * 256 + t;
  int v = (i < n) ? counts[i] : 0;
  int lane = t & 63, wid = t >> 6;
  int x = v;
#pragma unroll
  for (int d = 1; d < 64; d <<= 1) {
    int y = __shfl_up(x, d);
    if (lane >= d) x += y;
  }
  if (lane == 63) wsum[wid] = x;
  __syncthreads();
  int add = 0;
  for (int k = 0; k < wid; k++) add += wsum[k];
  int incl = x + add;
  if (i < n) local[i] = incl - v;
  if (t == 255) bsums[b] = incl;
}

__global__ void scan2_kernel(int* __restrict__ bsums, int nb) {
  __shared__ int buf[256];
  int t = threadIdx.x;
  int v = (t < nb) ? bsums[t] : 0;
  buf[t] = v;
  __syncthreads();
  for (int d = 1; d < 256; d <<= 1) {
    int a = (t >= d) ? buf[t - d] : 0;
    __syncthreads();
    buf[t] += a;
    __syncthreads();
  }
  if (t < nb) bsums[t] = buf[t] - v;  // exclusive
}

__global__ void scan3_kernel(const int* __restrict__ local, const int* __restrict__ bsums,
                             int* __restrict__ rp, int* __restrict__ cursor, int n) {
  int i = blockIdx.x * 256 + threadIdx.x;
  if (i > n) return;
  int v = (i < n) ? (local[i] + bsums[i >> 8]) : NE;
  rp[i] = v;
  if (i < n) cursor[i] = v;
}

// ---------------- CSR fill: bucket src ids by dst ----------------
__global__ void fill_kernel(const int* __restrict__ src32, const int* __restrict__ dst32,
                            int* __restrict__ cursor, int* __restrict__ ssrc) {
  int e = blockIdx.x * blockDim.x + threadIdx.x;
  if (e >= NE) return;
  int dst = dst32[e];
  int pos = atomicAdd(&cursor[dst], 1);
  ssrc[pos] = src32[e];
}

// ---------------- S = H0 + Esum @ W_hE^T + deg * b_h  (tiled, LDS-staged) ----------------
// 32 nodes/block, 256 thr. W_hE^T staged as float2 pairs [14][150] (16.8KB);
// Esum tile, deg, b_h in LDS. Each thread produces bf16 PAIRS (uint reads/writes).
#define CT_NODES 32
__global__ __launch_bounds__(256) void cterm_kernel(
    const float* __restrict__ Esum, const int* __restrict__ rp,
    const float* __restrict__ W_h, const float* __restrict__ b_h,
    const ushort_t* __restrict__ H0, ushort_t* __restrict__ Sb) {
  __shared__ float2 whe[14][152];       // [k][jp] = (W_hE[2jp][k], W_hE[2jp+1][k])
  __shared__ float2 bhs[152];
  __shared__ float es[CT_NODES][14];
  __shared__ float degs[CT_NODES];
  int tid = threadIdx.x;
  int nbase = blockIdx.x * CT_NODES;
  for (int u = tid; u < 14 * 150; u += 256) {
    int k = u / 150, jp = u % 150;
    whe[k][jp] = make_float2(W_h[(2 * jp) * (DH + DE) + DH + k],
                             W_h[(2 * jp + 1) * (DH + DE) + DH + k]);
  }
  if (tid < 150) bhs[tid] = make_float2(b_h[2 * tid], b_h[2 * tid + 1]);
  for (int u = tid; u < CT_NODES * 14; u += 256) {
    int nl = u / 14, k = u % 14;
    int n = nbase + nl;
    es[nl][k] = (n < NN) ? Esum[n * DE + k] : 0.f;
  }
  if (tid < CT_NODES) {
    int n = nbase + tid;
    degs[tid] = (n < NN) ? (float)(rp[n + 1] - rp[n]) : 0.f;
  }
  __syncthreads();
  for (int u = tid; u < CT_NODES * 150; u += 256) {
    int nl = u / 150, jp = u % 150;
    int n = nbase + nl;
    if (n >= NN) continue;
    unsigned int h = *(const unsigned int*)(H0 + (long)n * LDH + 2 * jp);
    float2 bp = bhs[jp];
    float d = degs[nl];
    float v0 = d * bp.x + u_lo(h);
    float v1 = d * bp.y + u_hi(h);
#pragma unroll
    for (int k = 0; k < DE; k++) {
      float2 wp = whe[k][jp];
      float e = es[nl][k];
      v0 += e * wp.x;
      v1 += e * wp.y;
    }
    *(unsigned int*)(Sb + (long)n * LDH + 2 * jp) =
        (unsigned int)f2bf(v0) | ((unsigned int)f2bf(v1) << 16);
  }
}

// ---------------- segment-sum via CSR gather: A[n] = sum_{e:dst=n} H[src_e] ----------------
// one wave per node; row = 320 bf16 = 640B = 40 lanes x 16B
__global__ void gather_kernel(const ushort_t* __restrict__ H, const int* __restrict__ rp,
                              const int* __restrict__ ssrc, ushort_t* __restrict__ A) {
  int wave = blockIdx.x * (blockDim.x >> 6) + (threadIdx.x >> 6);
  int lane = threadIdx.x & 63;
  if (wave >= NN || lane >= 40) return;
  int start = rp[wave], end = rp[wave + 1];
  float a0 = 0, a1 = 0, a2 = 0, a3 = 0, a4 = 0, a5 = 0, a6 = 0, a7 = 0;
  const uint4* base = (const uint4*)H;  // 40 uint4 per row
  int i = start;
  for (; i + 1 < end; i += 2) {
    int s0 = ssrc[i], s1 = ssrc[i + 1];
    uint4 x = base[(long)s0 * 40 + lane];
    uint4 y = base[(long)s1 * 40 + lane];
    a0 += u_lo(x.x); a1 += u_hi(x.x); a2 += u_lo(x.y); a3 += u_hi(x.y);
    a4 += u_lo(x.z); a5 += u_hi(x.z); a6 += u_lo(x.w); a7 += u_hi(x.w);
    a0 += u_lo(y.x); a1 += u_hi(y.x); a2 += u_lo(y.y); a3 += u_hi(y.y);
    a4 += u_lo(y.z); a5 += u_hi(y.z); a6 += u_lo(y.w); a7 += u_hi(y.w);
  }
  if (i < end) {
    int s0 = ssrc[i];
    uint4 x = base[(long)s0 * 40 + lane];
    a0 += u_lo(x.x); a1 += u_hi(x.x); a2 += u_lo(x.y); a3 += u_hi(x.y);
    a4 += u_lo(x.z); a5 += u_hi(x.z); a6 += u_lo(x.w); a7 += u_hi(x.w);
  }
  uint4 o;
  o.x = (unsigned int)f2bf(a0) | ((unsigned int)f2bf(a1) << 16);
  o.y = (unsigned int)f2bf(a2) | ((unsigned int)f2bf(a3) << 16);
  o.z = (unsigned int)f2bf(a4) | ((unsigned int)f2bf(a5) << 16);
  o.w = (unsigned int)f2bf(a6) | ((unsigned int)f2bf(a7) << 16);
  ((uint4*)A)[(long)wave * 40 + lane] = o;
}

// ---------------- bf16 MFMA GEMM, depth-2 prefetch, counted vmcnt (T3+T4) ----------------
// out = relu(A1@W1^T [+ A2@W2^T] + bias + add1)
// 512 thr = 8 waves; tile 64 rows x 304 cols. Wave w: col-frags cf=w+8i (i<3, cf<19),
// all 4 row-frags -> acc[4][3]. Per K-step (BK=32): 24 chunks of 1KB (4 A + 19 W + 1 dummy),
// 3 per wave -> uniform vmcnt counts. Triple-buffered LDS, loads for step s issued at s-2,
// waited with s_waitcnt vmcnt(3) (NEVER 0 in steady state) + raw s_barrier.
// Swizzle (round-5-verified, bank-conflict=0): slot' = slot ^ ((row>>1)&3), both sides.
__global__ __launch_bounds__(512) void gemm_kernel(
    const ushort_t* __restrict__ A1, int lda1, int nks1,
    const ushort_t* __restrict__ W1, int ldw1,
    const ushort_t* __restrict__ A2, int lda2, int nks2,
    const ushort_t* __restrict__ W2, int ldw2,
    const float* __restrict__ bias,
    const ushort_t* __restrict__ add1,
    ushort_t* __restrict__ outB,
    float* __restrict__ outF) {
  __shared__ ushort_t sA[3][2048];    // 3 x 4KB   (4 chunks x 512 shorts)
  __shared__ ushort_t sW[3][10240];   // 3 x 20KB  (20 chunks x 512 shorts)
  int tid = threadIdx.x;
  int w = tid >> 6, lane = tid & 63;
  int rowbase = blockIdx.x * 64;
  int nsteps = nks1 + nks2;

  f32x4 acc[4][3];
#pragma unroll
  for (int rf = 0; rf < 4; rf++)
#pragma unroll
    for (int i = 0; i < 3; i++) acc[rf][i] = (f32x4){0.f, 0.f, 0.f, 0.f};

  // staging lane mapping: 16B/lane; chunk = 16 rows x 64B; row-in-chunk = lane>>2, slot = lane&3
  int rsub = lane >> 2, slot = lane & 3;
  int sgo = (slot ^ ((rsub >> 1) & 3)) * 8;  // pre-swizzled global k-offset (shorts)
  // compute lane mapping
  int mrow = lane & 15, sub = lane >> 4;
  int ssw = (sub ^ ((mrow >> 1) & 3)) * 8;   // swizzled LDS k-offset (shorts)

  auto stage = [&](int s, int b) {
    int pass = (s >= nks1) ? 1 : 0;
    const ushort_t* Ap = pass ? A2 : A1;
    const ushort_t* Wp = pass ? W2 : W1;
    int lda = pass ? lda2 : lda1;
    int ldw = pass ? ldw2 : ldw1;
    int ks = pass ? (s - nks1) : s;
#pragma unroll
    for (int j = 0; j < 3; j++) {
      int c = w + 8 * j;
      if (c < 4) {                       // A chunk c: rows [c*16, c*16+16)
        int gr = rowbase + c * 16 + rsub;
        if (gr >= NN) gr = NN - 1;       // clamp (keeps vmcnt counts uniform)
        gload16(Ap + (long)gr * lda + ks * 32 + sgo, &sA[b][c * 512]);
      } else if (c < 23) {               // W chunk c-4: rows [(c-4)*16, ...+16)
        int row = (c - 4) * 16 + rsub;
        gload16(Wp + (long)row * ldw + ks * 32 + sgo, &sW[b][(c - 4) * 512]);
      } else {                           // dummy (uniform count): reload into unused slot 19
        int row = 288 + rsub;
        gload16(Wp + (long)row * ldw + ks * 32 + sgo, &sW[b][19 * 512]);
      }
    }
  };

  stage(0, 0);
  stage(1, 1);
  for (int s = 0; s < nsteps; s++) {
    int b = s % 3;
    if (s == nsteps - 1)
      asm volatile("s_waitcnt vmcnt(0)" ::: "memory");
    else
      asm volatile("s_waitcnt vmcnt(3)" ::: "memory");  // step-s loads (oldest) done
    __builtin_amdgcn_s_barrier();
    if (s + 2 < nsteps) stage(s + 2, (s + 2) % 3);      // issue early, land in 2 steps
    short8 af[4];
#pragma unroll
    for (int rf = 0; rf < 4; rf++)
      af[rf] = *(const short8*)(&sA[b][(rf * 16 + mrow) * 32 + ssw]);
#pragma unroll
    for (int i = 0; i < 3; i++) {
      int cf = w + 8 * i;
      if (cf < 19) {
        short8 bfr = *(const short8*)(&sW[b][(cf * 16 + mrow) * 32 + ssw]);
#pragma unroll
        for (int rf = 0; rf < 4; rf++)
          acc[rf][i] = __builtin_amdgcn_mfma_f32_16x16x32_bf16(af[rf], bfr, acc[rf][i], 0, 0, 0);
      }
    }
  }

  // ---------- epilogue: acc -> bf16 LDS bounce -> coalesced vector RMW ----------
  __syncthreads();                       // all ds_reads retired; reuse sW as bounce
  ushort_t* bounce = &sW[0][0];          // 64 x 304 shorts = 38.9KB (spans sW[0..1])
  int rloc = (lane >> 4) * 4;
  int cloc = lane & 15;
#pragma unroll
  for (int i = 0; i < 3; i++) {
    int cf = w + 8 * i;
    if (cf >= 19) continue;
    int col = cf * 16 + cloc;
#pragma unroll
    for (int rf = 0; rf < 4; rf++)
#pragma unroll
      for (int r = 0; r < 4; r++)
        bounce[(rf * 16 + rloc + r) * 304 + col] = f2bf(acc[rf][i][r]);
  }
  __syncthreads();
  for (int u = tid; u < 64 * 38; u += 512) {
    int rrow = u / 38, co = (u % 38) * 8;
    int gr = rowbase + rrow;
    if (gr >= NN) continue;
    short8 m = *(const short8*)(&bounce[rrow * 304 + co]);
    float v[8];
#pragma unroll
    for (int j = 0; j < 8; j++) v[j] = bf2f((ushort_t)m[j]);
    if (bias) {
#pragma unroll
      for (int j = 0; j < 8; j++) { int gc = co + j; if (gc < DH) v[j] += bias[gc]; }
    }
    if (add1) {
      short8 a = *(const short8*)(add1 + (long)gr * LDH + co);
#pragma unroll
      for (int j = 0; j < 8; j++) v[j] += bf2f((ushort_t)a[j]);
    }
#pragma unroll
    for (int j = 0; j < 8; j++) v[j] = fmaxf(v[j], 0.f);
    if (outB) {
      short8 o;
#pragma unroll
      for (int j = 0; j < 8; j++) o[j] = (short)f2bf(v[j]);
      *(short8*)(outB + (long)gr * LDH + co) = o;
    }
    if (outF) {
#pragma unroll
      for (int j = 0; j < 8; j++) { int gc = co + j; if (gc < DH) outF[(long)gr * DH + gc] = v[j]; }
    }
  }
}

extern "C" void kernel_launch(void* const* d_in, const int* in_sizes, int n_in,
                              void* d_out, int out_size, void* d_ws, size_t ws_size,
                              hipStream_t stream) {
  const float* V   = (const float*)d_in[0];
  const float* E   = (const float*)d_in[1];
  const void*  ei  = d_in[2];
  const float* W_i = (const float*)d_in[3];
  const float* b_i = (const float*)d_in[4];
  const float* W_h = (const float*)d_in[5];
  const float* b_h = (const float*)d_in[6];
  const float* W_o = (const float*)d_in[7];
  const float* b_o = (const float*)d_in[8];
  float* out = (float*)d_out;

  char* ws = (char*)d_ws;
  size_t off = 0;
  auto alloc = [&](size_t bytes) {
    void* p = ws + off;
    off = (off + bytes + 255) & ~(size_t)255;
    return p;
  };
  ushort_t* Vbf  = (ushort_t*)alloc((size_t)NN * 160 * 2);
  ushort_t* Hb   = (ushort_t*)alloc((size_t)NN * LDH * 2);
  ushort_t* Ab   = (ushort_t*)alloc((size_t)NN * LDH * 2);
  ushort_t* Sb   = (ushort_t*)alloc((size_t)NN * LDH * 2);
  ushort_t* Wib  = (ushort_t*)alloc((size_t)304 * 160 * 2);
  ushort_t* WhHb = (ushort_t*)alloc((size_t)304 * 320 * 2);
  ushort_t* WoVb = (ushort_t*)alloc((size_t)304 * 160 * 2);
  ushort_t* WoHb = (ushort_t*)alloc((size_t)304 * 320 * 2);
  float*  Esum   = (float*)alloc((size_t)NN * DE * 4);
  int* counts    = (int*)alloc((size_t)NN * 4);
  int* rp        = (int*)alloc((size_t)(NN + 4) * 4);
  int* cursor    = (int*)alloc((size_t)NN * 4);
  int* ssrc      = (int*)alloc((size_t)NE * 4);
  int* src32     = (int*)alloc((size_t)NE * 4);
  int* dst32     = (int*)alloc((size_t)NE * 4);
  int* slocal    = (int*)alloc((size_t)NN * 4);
  int* sbsums    = (int*)alloc((size_t)256 * 4);
  int* flag      = (int*)alloc(256);

  // zero-init: K-pad columns of Hb must be 0 (gather + GEMM-A reads); Esum/counts accumulate
  hipMemsetAsync(Hb, 0, (size_t)NN * LDH * 2, stream);
  hipMemsetAsync(Esum, 0, (size_t)NN * DE * 4, stream);
  hipMemsetAsync(counts, 0, (size_t)NN * 4, stream);

  // normalize edge_index to int32 src/dst regardless of on-device dtype
  detect_kernel<<<1, 256, 0, stream>>>((const int*)ei, flag);
  decode_kernel<<<(NE + 255) / 256, 256, 0, stream>>>(ei, flag, src32, dst32);

  auto conv = [&](const float* src, int sld, int coff, int rows, int cols,
                  ushort_t* dst, int dld, int drows) {
    long total = (long)drows * dld;
    convert_pad_kernel<<<(int)((total + 255) / 256), 256, 0, stream>>>(
        src, sld, coff, rows, cols, dst, dld, total);
  };
  conv(V, DV, 0, NN, DV, Vbf, 160, NN);
  conv(W_i, DV, 0, DH, DV, Wib, 160, 304);
  conv(W_h, DH + DE, 0, DH, DH, WhHb, 320, 304);
  conv(W_o, DV + DH, 0, DH, DV, WoVb, 160, 304);
  conv(W_o, DV + DH, DV, DH, DH, WoHb, 320, 304);

  esum_count_kernel<<<NE * 16 / 256, 256, 0, stream>>>(dst32, E, Esum, counts);

  // H0 = relu(V @ W_i^T + b_i) -> Hb (iteration state; also read by cterm as H0)
  gemm_kernel<<<(NN + 63) / 64, 512, 0, stream>>>(
      Vbf, 160, 5, Wib, 160, nullptr, 0, 0, nullptr, 0,
      b_i, nullptr, Hb, nullptr);

  // parallel scan of counts -> rp / cursor
  scan1_kernel<<<(NN + 255) / 256, 256, 0, stream>>>(counts, slocal, sbsums, NN);
  scan2_kernel<<<1, 256, 0, stream>>>(sbsums, (NN + 255) / 256);
  scan3_kernel<<<(NN + 256) / 256, 256, 0, stream>>>(slocal, sbsums, rp, cursor, NN);

  fill_kernel<<<(NE + 255) / 256, 256, 0, stream>>>(src32, dst32, cursor, ssrc);
  // S = H0 + Esum@W_hE^T + deg*b_h   (reads Hb == H0 here)
  cterm_kernel<<<(NN + CT_NODES - 1) / CT_NODES, 256, 0, stream>>>(Esum, rp, W_h, b_h, Hb, Sb);

  for (int it = 0; it < 2; it++) {
    gather_kernel<<<NN / 4, 256, 0, stream>>>(Hb, rp, ssrc, Ab);
    // H = relu(S + A @ W_hH^T)
    gemm_kernel<<<(NN + 63) / 64, 512, 0, stream>>>(
        Ab, 320, 10, WhHb, 320, nullptr, 0, 0, nullptr, 0,
        nullptr, Sb, Hb, nullptr);
  }
  gather_kernel<<<NN / 4, 256, 0, stream>>>(Hb, rp, ssrc, Ab);
  // H_v = relu(V @ W_oV^T + M_v @ W_oH^T + b_o) -> f32 d_out
  gemm_kernel<<<(NN + 63) / 64, 512, 0, stream>>>(
      Vbf, 160, 5, WoVb, 160, Ab, 320, 10, WoHb, 320,
      b_o, nullptr, nullptr, out);
}

// Round 10
// 688.633 us; speedup vs baseline: 2.0525x; 1.0578x over previous
//
#include <hip/hip_runtime.h>
#include <hip/hip_bf16.h>
#include <stdint.h>

// Problem constants (from reference)
#define NN 50000
#define NE 800000
#define DV 133
#define DE 14
#define DH 300
#define LDH 320   // padded row stride (shorts) for all node-state buffers

typedef unsigned short ushort_t;
typedef __attribute__((ext_vector_type(8))) short short8;
typedef __attribute__((ext_vector_type(4))) float f32x4;

__device__ __forceinline__ float bf2f(ushort_t u) {
  union { unsigned int i; float f; } v; v.i = ((unsigned int)u) << 16; return v.f;
}
__device__ __forceinline__ ushort_t f2bf(float f) {
  union { unsigned int i; float f; } v; v.f = f;
  unsigned int u = v.i;
  return (ushort_t)((u + 0x7fffu + ((u >> 16) & 1u)) >> 16);
}
__device__ __forceinline__ float u_lo(unsigned int u) {
  union { unsigned int i; float f; } v; v.i = u << 16; return v.f;
}
__device__ __forceinline__ float u_hi(unsigned int u) {
  union { unsigned int i; float f; } v; v.i = u & 0xffff0000u; return v.f;
}

// async global->LDS, 16B per lane; LDS dest = wave-uniform base + lane*16
__device__ __forceinline__ void gload16(const void* g, void* l) {
  __builtin_amdgcn_global_load_lds(
      (const __attribute__((address_space(1))) unsigned int*)g,
      (__attribute__((address_space(3))) unsigned int*)l, 16, 0, 0);
}

// ---------------- edge_index dtype detection (int64 vs int32) ----------------
__global__ void detect_kernel(const int* __restrict__ ei32, int* __restrict__ flag) {
  __shared__ int s_or;
  if (threadIdx.x == 0) s_or = 0;
  __syncthreads();
  int v = ei32[2 * threadIdx.x + 1] | ei32[2 * (threadIdx.x + 256) + 1] |
          ei32[2 * (threadIdx.x + 512) + 1] | ei32[2 * (threadIdx.x + 768) + 1];
  if (v) atomicOr(&s_or, 1);
  __syncthreads();
  if (threadIdx.x == 0) *flag = (s_or == 0) ? 1 : 0;
}

// decode edge_index to int32 src/dst AND count in-degrees (counts must be pre-zeroed)
__global__ void decode_kernel(const void* __restrict__ ei_raw, const int* __restrict__ flag,
                              int* __restrict__ src32, int* __restrict__ dst32,
                              int* __restrict__ counts) {
  int e = blockIdx.x * blockDim.x + threadIdx.x;
  if (e >= NE) return;
  int s, d;
  if (*flag) {
    const long long* p = (const long long*)ei_raw;
    s = (int)p[e];
    d = (int)p[NE + e];
  } else {
    const int* p = (const int*)ei_raw;
    s = p[e];
    d = p[NE + e];
  }
  src32[e] = s;
  dst32[e] = d;
  atomicAdd(&counts[d], 1);
}

// ---------------- conversion: f32 submatrix -> zero-padded bf16 ----------------
__global__ void convert_pad_kernel(const float* __restrict__ src, int src_ld, int col_off,
                                   int rows, int cols, ushort_t* __restrict__ dst, int dst_ld,
                                   long total) {
  long gid = (long)blockIdx.x * blockDim.x + threadIdx.x;
  if (gid >= total) return;
  int r = (int)(gid / dst_ld), c = (int)(gid % dst_ld);
  float v = (r < rows && c < cols) ? src[(long)r * src_ld + col_off + c] : 0.f;
  dst[gid] = f2bf(v);
}

// ---------------- parallel scan (3 kernels) ----------------
__global__ void scan1_kernel(const int* __restrict__ counts, int* __restrict__ local,
                             int* __restrict__ bsums, int n) {
  __shared__ int wsum[4];
  int b = blockIdx.x, t = threadIdx.x;
  int i = b * 256 + t;
  int v = (i < n) ? counts[i] : 0;
  int lane = t & 63, wid = t >> 6;
  int x = v;
#pragma unroll
  for (int d = 1; d < 64; d <<= 1) {
    int y = __shfl_up(x, d);
    if (lane >= d) x += y;
  }
  if (lane == 63) wsum[wid] = x;
  __syncthreads();
  int add = 0;
  for (int k = 0; k < wid; k++) add += wsum[k];
  int incl = x + add;
  if (i < n) local[i] = incl - v;
  if (t == 255) bsums[b] = incl;
}

__global__ void scan2_kernel(int* __restrict__ bsums, int nb) {
  __shared__ int buf[256];
  int t = threadIdx.x;
  int v = (t < nb) ? bsums[t] : 0;
  buf[t] = v;
  __syncthreads();
  for (int d = 1; d < 256; d <<= 1) {
    int a = (t >= d) ? buf[t - d] : 0;
    __syncthreads();
    buf[t] += a;
    __syncthreads();
  }
  if (t < nb) bsums[t] = buf[t] - v;  // exclusive
}

__global__ void scan3_kernel(const int* __restrict__ local, const int* __restrict__ bsums,
                             int* __restrict__ rp, int* __restrict__ cursor, int n) {
  int i = blockIdx.x * 256 + threadIdx.x;
  if (i > n) return;
  int v = (i < n) ? (local[i] + bsums[i >> 8]) : NE;
  rp[i] = v;
  if (i < n) cursor[i] = v;
}

// ---------------- CSR fill: bucket (src id, edge id) by dst ----------------
__global__ void fill_kernel(const int* __restrict__ src32, const int* __restrict__ dst32,
                            int* __restrict__ cursor, int* __restrict__ ssrc,
                            int* __restrict__ sedge) {
  int e = blockIdx.x * blockDim.x + threadIdx.x;
  if (e >= NE) return;
  int dst = dst32[e];
  int pos = atomicAdd(&cursor[dst], 1);
  ssrc[pos] = src32[e];
  sedge[pos] = e;
}

// ---------------- Esum[n][k] = sum over CSR edges of E[eid][k]  (no atomics) ----------------
// one wave per node; 64 lanes = 4 edge-slots x 16 k-slots (k<14 useful)
__global__ void esum_csr_kernel(const float* __restrict__ E, const int* __restrict__ rp,
                                const int* __restrict__ sedge, float* __restrict__ Esum) {
  int wave = blockIdx.x * (blockDim.x >> 6) + (threadIdx.x >> 6);
  int lane = threadIdx.x & 63;
  if (wave >= NN) return;
  int start = rp[wave], end = rp[wave + 1];
  int k = lane & 15, slot = lane >> 4;
  float acc = 0.f;
  for (int i = start + slot; i < end; i += 4) {
    int eid = sedge[i];
    if (k < DE) acc += E[(long)eid * DE + k];
  }
  acc += __shfl_xor(acc, 16);
  acc += __shfl_xor(acc, 32);
  if (lane < DE) Esum[(long)wave * DE + lane] = acc;
}

// ---------------- S = H0 + Esum @ W_hE^T + deg * b_h  (tiled, LDS-staged) ----------------
// 32 nodes/block, 256 thr. W_hE^T staged as float2 pairs [14][150] (16.8KB);
// Esum tile, deg, b_h in LDS. Each thread produces bf16 PAIRS (uint reads/writes).
#define CT_NODES 32
__global__ __launch_bounds__(256) void cterm_kernel(
    const float* __restrict__ Esum, const int* __restrict__ rp,
    const float* __restrict__ W_h, const float* __restrict__ b_h,
    const ushort_t* __restrict__ H0, ushort_t* __restrict__ Sb) {
  __shared__ float2 whe[14][152];       // [k][jp] = (W_hE[2jp][k], W_hE[2jp+1][k])
  __shared__ float2 bhs[152];
  __shared__ float es[CT_NODES][14];
  __shared__ float degs[CT_NODES];
  int tid = threadIdx.x;
  int nbase = blockIdx.x * CT_NODES;
  for (int u = tid; u < 14 * 150; u += 256) {
    int k = u / 150, jp = u % 150;
    whe[k][jp] = make_float2(W_h[(2 * jp) * (DH + DE) + DH + k],
                             W_h[(2 * jp + 1) * (DH + DE) + DH + k]);
  }
  if (tid < 150) bhs[tid] = make_float2(b_h[2 * tid], b_h[2 * tid + 1]);
  for (int u = tid; u < CT_NODES * 14; u += 256) {
    int nl = u / 14, k = u % 14;
    int n = nbase + nl;
    es[nl][k] = (n < NN) ? Esum[n * DE + k] : 0.f;
  }
  if (tid < CT_NODES) {
    int n = nbase + tid;
    degs[tid] = (n < NN) ? (float)(rp[n + 1] - rp[n]) : 0.f;
  }
  __syncthreads();
  for (int u = tid; u < CT_NODES * 150; u += 256) {
    int nl = u / 150, jp = u % 150;
    int n = nbase + nl;
    if (n >= NN) continue;
    unsigned int h = *(const unsigned int*)(H0 + (long)n * LDH + 2 * jp);
    float2 bp = bhs[jp];
    float d = degs[nl];
    float v0 = d * bp.x + u_lo(h);
    float v1 = d * bp.y + u_hi(h);
#pragma unroll
    for (int k = 0; k < DE; k++) {
      float2 wp = whe[k][jp];
      float e = es[nl][k];
      v0 += e * wp.x;
      v1 += e * wp.y;
    }
    *(unsigned int*)(Sb + (long)n * LDH + 2 * jp) =
        (unsigned int)f2bf(v0) | ((unsigned int)f2bf(v1) << 16);
  }
}

// ---------------- segment-sum via CSR gather: A[n] = sum_{e:dst=n} H[src_e] ----------------
// one wave per node; row = 320 bf16 = 640B = 40 lanes x 16B
__global__ void gather_kernel(const ushort_t* __restrict__ H, const int* __restrict__ rp,
                              const int* __restrict__ ssrc, ushort_t* __restrict__ A) {
  int wave = blockIdx.x * (blockDim.x >> 6) + (threadIdx.x >> 6);
  int lane = threadIdx.x & 63;
  if (wave >= NN || lane >= 40) return;
  int start = rp[wave], end = rp[wave + 1];
  float a0 = 0, a1 = 0, a2 = 0, a3 = 0, a4 = 0, a5 = 0, a6 = 0, a7 = 0;
  const uint4* base = (const uint4*)H;  // 40 uint4 per row
  int i = start;
  for (; i + 1 < end; i += 2) {
    int s0 = ssrc[i], s1 = ssrc[i + 1];
    uint4 x = base[(long)s0 * 40 + lane];
    uint4 y = base[(long)s1 * 40 + lane];
    a0 += u_lo(x.x); a1 += u_hi(x.x); a2 += u_lo(x.y); a3 += u_hi(x.y);
    a4 += u_lo(x.z); a5 += u_hi(x.z); a6 += u_lo(x.w); a7 += u_hi(x.w);
    a0 += u_lo(y.x); a1 += u_hi(y.x); a2 += u_lo(y.y); a3 += u_hi(y.y);
    a4 += u_lo(y.z); a5 += u_hi(y.z); a6 += u_lo(y.w); a7 += u_hi(y.w);
  }
  if (i < end) {
    int s0 = ssrc[i];
    uint4 x = base[(long)s0 * 40 + lane];
    a0 += u_lo(x.x); a1 += u_hi(x.x); a2 += u_lo(x.y); a3 += u_hi(x.y);
    a4 += u_lo(x.z); a5 += u_hi(x.z); a6 += u_lo(x.w); a7 += u_hi(x.w);
  }
  uint4 o;
  o.x = (unsigned int)f2bf(a0) | ((unsigned int)f2bf(a1) << 16);
  o.y = (unsigned int)f2bf(a2) | ((unsigned int)f2bf(a3) << 16);
  o.z = (unsigned int)f2bf(a4) | ((unsigned int)f2bf(a5) << 16);
  o.w = (unsigned int)f2bf(a6) | ((unsigned int)f2bf(a7) << 16);
  ((uint4*)A)[(long)wave * 40 + lane] = o;
}

// ---------------- bf16 MFMA GEMM, depth-2 prefetch, counted vmcnt (T3+T4) ----------------
// out = relu(A1@W1^T [+ A2@W2^T] + bias + add1)
// 512 thr = 8 waves; tile 64 rows x 304 cols. Wave w: col-frags cf=w+8i (i<3, cf<19),
// all 4 row-frags -> acc[4][3]. Per K-step (BK=32): 24 chunks of 1KB (4 A + 19 W + 1 dummy),
// 3 per wave -> uniform vmcnt counts. Triple-buffered LDS, loads for step s issued at s-2,
// waited with s_waitcnt vmcnt(3) (NEVER 0 in steady state) + raw s_barrier.
// Swizzle (round-5-verified, bank-conflict=0): slot' = slot ^ ((row>>1)&3), both sides.
__global__ __launch_bounds__(512) void gemm_kernel(
    const ushort_t* __restrict__ A1, int lda1, int nks1,
    const ushort_t* __restrict__ W1, int ldw1,
    const ushort_t* __restrict__ A2, int lda2, int nks2,
    const ushort_t* __restrict__ W2, int ldw2,
    const float* __restrict__ bias,
    const ushort_t* __restrict__ add1,
    ushort_t* __restrict__ outB,
    float* __restrict__ outF) {
  __shared__ ushort_t sA[3][2048];    // 3 x 4KB   (4 chunks x 512 shorts)
  __shared__ ushort_t sW[3][10240];   // 3 x 20KB  (20 chunks x 512 shorts)
  int tid = threadIdx.x;
  int w = tid >> 6, lane = tid & 63;
  int rowbase = blockIdx.x * 64;
  int nsteps = nks1 + nks2;

  f32x4 acc[4][3];
#pragma unroll
  for (int rf = 0; rf < 4; rf++)
#pragma unroll
    for (int i = 0; i < 3; i++) acc[rf][i] = (f32x4){0.f, 0.f, 0.f, 0.f};

  // staging lane mapping: 16B/lane; chunk = 16 rows x 64B; row-in-chunk = lane>>2, slot = lane&3
  int rsub = lane >> 2, slot = lane & 3;
  int sgo = (slot ^ ((rsub >> 1) & 3)) * 8;  // pre-swizzled global k-offset (shorts)
  // compute lane mapping
  int mrow = lane & 15, sub = lane >> 4;
  int ssw = (sub ^ ((mrow >> 1) & 3)) * 8;   // swizzled LDS k-offset (shorts)

  auto stage = [&](int s, int b) {
    int pass = (s >= nks1) ? 1 : 0;
    const ushort_t* Ap = pass ? A2 : A1;
    const ushort_t* Wp = pass ? W2 : W1;
    int lda = pass ? lda2 : lda1;
    int ldw = pass ? ldw2 : ldw1;
    int ks = pass ? (s - nks1) : s;
#pragma unroll
    for (int j = 0; j < 3; j++) {
      int c = w + 8 * j;
      if (c < 4) {                       // A chunk c: rows [c*16, c*16+16)
        int gr = rowbase + c * 16 + rsub;
        if (gr >= NN) gr = NN - 1;       // clamp (keeps vmcnt counts uniform)
        gload16(Ap + (long)gr * lda + ks * 32 + sgo, &sA[b][c * 512]);
      } else if (c < 23) {               // W chunk c-4: rows [(c-4)*16, ...+16)
        int row = (c - 4) * 16 + rsub;
        gload16(Wp + (long)row * ldw + ks * 32 + sgo, &sW[b][(c - 4) * 512]);
      } else {                           // dummy (uniform count): reload into unused slot 19
        int row = 288 + rsub;
        gload16(Wp + (long)row * ldw + ks * 32 + sgo, &sW[b][19 * 512]);
      }
    }
  };

  stage(0, 0);
  stage(1, 1);
  for (int s = 0; s < nsteps; s++) {
    int b = s % 3;
    if (s == nsteps - 1)
      asm volatile("s_waitcnt vmcnt(0)" ::: "memory");
    else
      asm volatile("s_waitcnt vmcnt(3)" ::: "memory");  // step-s loads (oldest) done
    __builtin_amdgcn_s_barrier();
    if (s + 2 < nsteps) stage(s + 2, (s + 2) % 3);      // issue early, land in 2 steps
    short8 af[4];
#pragma unroll
    for (int rf = 0; rf < 4; rf++)
      af[rf] = *(const short8*)(&sA[b][(rf * 16 + mrow) * 32 + ssw]);
#pragma unroll
    for (int i = 0; i < 3; i++) {
      int cf = w + 8 * i;
      if (cf < 19) {
        short8 bfr = *(const short8*)(&sW[b][(cf * 16 + mrow) * 32 + ssw]);
#pragma unroll
        for (int rf = 0; rf < 4; rf++)
          acc[rf][i] = __builtin_amdgcn_mfma_f32_16x16x32_bf16(af[rf], bfr, acc[rf][i], 0, 0, 0);
      }
    }
  }

  // ---------- epilogue: acc -> bf16 LDS bounce -> coalesced vector RMW ----------
  __syncthreads();                       // all ds_reads retired; reuse sW as bounce
  ushort_t* bounce = &sW[0][0];          // 64 x 304 shorts = 38.9KB (spans sW[0..1])
  int rloc = (lane >> 4) * 4;
  int cloc = lane & 15;
#pragma unroll
  for (int i = 0; i < 3; i++) {
    int cf = w + 8 * i;
    if (cf >= 19) continue;
    int col = cf * 16 + cloc;
#pragma unroll
    for (int rf = 0; rf < 4; rf++)
#pragma unroll
      for (int r = 0; r < 4; r++)
        bounce[(rf * 16 + rloc + r) * 304 + col] = f2bf(acc[rf][i][r]);
  }
  __syncthreads();
  for (int u = tid; u < 64 * 38; u += 512) {
    int rrow = u / 38, co = (u % 38) * 8;
    int gr = rowbase + rrow;
    if (gr >= NN) continue;
    short8 m = *(const short8*)(&bounce[rrow * 304 + co]);
    float v[8];
#pragma unroll
    for (int j = 0; j < 8; j++) v[j] = bf2f((ushort_t)m[j]);
    if (bias) {
#pragma unroll
      for (int j = 0; j < 8; j++) { int gc = co + j; if (gc < DH) v[j] += bias[gc]; }
    }
    if (add1) {
      short8 a = *(const short8*)(add1 + (long)gr * LDH + co);
#pragma unroll
      for (int j = 0; j < 8; j++) v[j] += bf2f((ushort_t)a[j]);
    }
#pragma unroll
    for (int j = 0; j < 8; j++) v[j] = fmaxf(v[j], 0.f);
    if (outB) {
      short8 o;
#pragma unroll
      for (int j = 0; j < 8; j++) o[j] = (short)f2bf(v[j]);
      *(short8*)(outB + (long)gr * LDH + co) = o;
    }
    if (outF) {
#pragma unroll
      for (int j = 0; j < 8; j++) { int gc = co + j; if (gc < DH) outF[(long)gr * DH + gc] = v[j]; }
    }
  }
}

extern "C" void kernel_launch(void* const* d_in, const int* in_sizes, int n_in,
                              void* d_out, int out_size, void* d_ws, size_t ws_size,
                              hipStream_t stream) {
  const float* V   = (const float*)d_in[0];
  const float* E   = (const float*)d_in[1];
  const void*  ei  = d_in[2];
  const float* W_i = (const float*)d_in[3];
  const float* b_i = (const float*)d_in[4];
  const float* W_h = (const float*)d_in[5];
  const float* b_h = (const float*)d_in[6];
  const float* W_o = (const float*)d_in[7];
  const float* b_o = (const float*)d_in[8];
  float* out = (float*)d_out;

  char* ws = (char*)d_ws;
  size_t off = 0;
  auto alloc = [&](size_t bytes) {
    void* p = ws + off;
    off = (off + bytes + 255) & ~(size_t)255;
    return p;
  };
  ushort_t* Vbf  = (ushort_t*)alloc((size_t)NN * 160 * 2);
  ushort_t* Hb   = (ushort_t*)alloc((size_t)NN * LDH * 2);
  ushort_t* Ab   = (ushort_t*)alloc((size_t)NN * LDH * 2);
  ushort_t* Sb   = (ushort_t*)alloc((size_t)NN * LDH * 2);
  ushort_t* Wib  = (ushort_t*)alloc((size_t)304 * 160 * 2);
  ushort_t* WhHb = (ushort_t*)alloc((size_t)304 * 320 * 2);
  ushort_t* WoVb = (ushort_t*)alloc((size_t)304 * 160 * 2);
  ushort_t* WoHb = (ushort_t*)alloc((size_t)304 * 320 * 2);
  float*  Esum   = (float*)alloc((size_t)NN * DE * 4);
  int* counts    = (int*)alloc((size_t)NN * 4);
  int* rp        = (int*)alloc((size_t)(NN + 4) * 4);
  int* cursor    = (int*)alloc((size_t)NN * 4);
  int* ssrc      = (int*)alloc((size_t)NE * 4);
  int* sedge     = (int*)alloc((size_t)NE * 4);
  int* src32     = (int*)alloc((size_t)NE * 4);
  int* dst32     = (int*)alloc((size_t)NE * 4);
  int* slocal    = (int*)alloc((size_t)NN * 4);
  int* sbsums    = (int*)alloc((size_t)256 * 4);
  int* flag      = (int*)alloc(256);

  // zero-init: K-pad columns of Hb must be 0 (gather + GEMM-A reads); counts accumulate
  hipMemsetAsync(Hb, 0, (size_t)NN * LDH * 2, stream);
  hipMemsetAsync(counts, 0, (size_t)NN * 4, stream);

  // normalize edge_index to int32 src/dst (and count in-degrees)
  detect_kernel<<<1, 256, 0, stream>>>((const int*)ei, flag);
  decode_kernel<<<(NE + 255) / 256, 256, 0, stream>>>(ei, flag, src32, dst32, counts);

  auto conv = [&](const float* src, int sld, int coff, int rows, int cols,
                  ushort_t* dst, int dld, int drows) {
    long total = (long)drows * dld;
    convert_pad_kernel<<<(int)((total + 255) / 256), 256, 0, stream>>>(
        src, sld, coff, rows, cols, dst, dld, total);
  };
  conv(V, DV, 0, NN, DV, Vbf, 160, NN);
  conv(W_i, DV, 0, DH, DV, Wib, 160, 304);
  conv(W_h, DH + DE, 0, DH, DH, WhHb, 320, 304);
  conv(W_o, DV + DH, 0, DH, DV, WoVb, 160, 304);
  conv(W_o, DV + DH, DV, DH, DH, WoHb, 320, 304);

  // H0 = relu(V @ W_i^T + b_i) -> Hb (iteration state; also read by cterm as H0)
  gemm_kernel<<<(NN + 63) / 64, 512, 0, stream>>>(
      Vbf, 160, 5, Wib, 160, nullptr, 0, 0, nullptr, 0,
      b_i, nullptr, Hb, nullptr);

  // parallel scan of counts -> rp / cursor
  scan1_kernel<<<(NN + 255) / 256, 256, 0, stream>>>(counts, slocal, sbsums, NN);
  scan2_kernel<<<1, 256, 0, stream>>>(sbsums, (NN + 255) / 256);
  scan3_kernel<<<(NN + 256) / 256, 256, 0, stream>>>(slocal, sbsums, rp, cursor, NN);

  fill_kernel<<<(NE + 255) / 256, 256, 0, stream>>>(src32, dst32, cursor, ssrc, sedge);

  // Esum via CSR gather (no atomics), then S = H0 + Esum@W_hE^T + deg*b_h
  esum_csr_kernel<<<NN / 4, 256, 0, stream>>>(E, rp, sedge, Esum);
  cterm_kernel<<<(NN + CT_NODES - 1) / CT_NODES, 256, 0, stream>>>(Esum, rp, W_h, b_h, Hb, Sb);

  for (int it = 0; it < 2; it++) {
    gather_kernel<<<NN / 4, 256, 0, stream>>>(Hb, rp, ssrc, Ab);
    // H = relu(S + A @ W_hH^T)
    gemm_kernel<<<(NN + 63) / 64, 512, 0, stream>>>(
        Ab, 320, 10, WhHb, 320, nullptr, 0, 0, nullptr, 0,
        nullptr, Sb, Hb, nullptr);
  }
  gather_kernel<<<NN / 4, 256, 0, stream>>>(Hb, rp, ssrc, Ab);
  // H_v = relu(V @ W_oV^T + M_v @ W_oH^T + b_o) -> f32 d_out
  gemm_kernel<<<(NN + 63) / 64, 512, 0, stream>>>(
      Vbf, 160, 5, WoVb, 160, Ab, 320, 10, WoHb, 320,
      b_o, nullptr, nullptr, out);
}